// Round 9
// baseline (321.395 us; speedup 1.0000x reference)
//
#include <hip/hip_runtime.h>
#include <math.h>

#define PP    1024
#define NPT   128
#define NN2   16384
#define THRESH 0.05f
#define MAXC  1500
#define EPSD  1e-5
#define RRD   (0.1*0.1)
#define NEGF  -3.0e38f
#define MAXCPB 384      // mutual-top3 per proposal is mathematically <= 3*128
#define SELCAP 4096u

// ---- workspace byte offsets (everything written before read; no memsets) ----
#define OFF_CCNT  0          // u32[1024]                  -> 4096
#define OFF_ICNT  4096       // int[1024]                  -> 8192
#define OFF_TRANS 8192       // double[1024*12]            -> 106496
#define OFF_POOL  106496     // float[15000]               -> 166496
#define OFF_HDR   166496     // u32[16]: 0=total 1=selCnt 2=cutbin -> 166560
#define OFF_SEL   166560     // u64[4096]                  -> 199328
#define OFF_PHIST 199328     // u32[64*4096]               -> 1247904
#define OFF_CLIST 1247904    // u64[1024*384]              -> 4393632

// ---------------- branchless top-3 helpers ----------------
__device__ inline void top3_upd(float v, float& a, float& b, float& c) {
  float m1 = fminf(a, v);
  a = fmaxf(a, v);
  float m2 = fminf(b, m1);
  b = fmaxf(b, m1);
  c = fmaxf(c, m2);
}
__device__ inline void merge3(float& a, float& b, float& c, float x0, float x1, float x2) {
  float z0 = fmaxf(a, x0);
  float z1 = fmaxf(fminf(a, x0), fmaxf(b, x1));
  float z2 = fmaxf(fmaxf(c, x2), fmaxf(fminf(b, x0), fminf(a, x1)));
  a = z0; b = z1; c = z2;
}

// sortable float encoding (enc ascending == v ascending)
__device__ inline unsigned enc_f(float v) {
  unsigned b = __float_as_uint(v);
  return (b & 0x80000000u) ? ~b : (b | 0x80000000u);
}
__device__ inline float dec_f(unsigned enc) {
  unsigned b = (enc & 0x80000000u) ? (enc ^ 0x80000000u) : ~enc;
  return __uint_as_float(b);
}

// ---------------- Jacobi fallback (rare: near-degenerate eigenvalue gap) --------
__device__ inline void jacobi4(double A[4][4], double V[4][4]) {
  for (int i = 0; i < 4; ++i)
    for (int j = 0; j < 4; ++j) V[i][j] = (i == j) ? 1.0 : 0.0;
  const int PI_[6] = {0, 0, 0, 1, 1, 2};
  const int QI_[6] = {1, 2, 3, 2, 3, 3};
  for (int sweep = 0; sweep < 30; ++sweep) {
    double off = fabs(A[0][1]) + fabs(A[0][2]) + fabs(A[0][3]) +
                 fabs(A[1][2]) + fabs(A[1][3]) + fabs(A[2][3]);
    double dia = fabs(A[0][0]) + fabs(A[1][1]) + fabs(A[2][2]) + fabs(A[3][3]);
    if (off <= 1e-14 * (dia + 1e-300)) break;
    for (int r = 0; r < 6; ++r) {
      int p = PI_[r], q = QI_[r];
      double apq = A[p][q];
      if (fabs(apq) <= 1e-18 * (fabs(A[p][p]) + fabs(A[q][q]) + 1e-300)) continue;
      double theta = (A[q][q] - A[p][p]) / (2.0 * apq);
      double t = ((theta >= 0.0) ? 1.0 : -1.0) / (fabs(theta) + sqrt(1.0 + theta * theta));
      double c = 1.0 / sqrt(1.0 + t * t);
      double s = t * c;
      for (int k = 0; k < 4; ++k) {
        double akp = A[k][p], akq = A[k][q];
        A[k][p] = c * akp - s * akq;
        A[k][q] = s * akp + c * akq;
      }
      for (int k = 0; k < 4; ++k) {
        double apk = A[p][k], aqk = A[q][k];
        A[p][k] = c * apk - s * aqk;
        A[q][k] = s * apk + c * aqk;
      }
      for (int k = 0; k < 4; ++k) {
        double vkp = V[k][p], vkq = V[k][q];
        V[k][p] = c * vkp - s * vkq;
        V[k][q] = s * vkp + c * vkq;
      }
    }
  }
}

// signed 3x3 cofactor of 4x4 M, removing row rr / col cc
__device__ inline double cof3(const double M[4][4], int rr, int cc) {
  int ri[3], ci[3];
  int n = 0;
  for (int i = 0; i < 4; ++i) if (i != rr) ri[n++] = i;
  n = 0;
  for (int j = 0; j < 4; ++j) if (j != cc) ci[n++] = j;
  double a = M[ri[0]][ci[0]], b = M[ri[0]][ci[1]], c = M[ri[0]][ci[2]];
  double d = M[ri[1]][ci[0]], e = M[ri[1]][ci[1]], f = M[ri[1]][ci[2]];
  double g = M[ri[2]][ci[0]], h = M[ri[2]][ci[1]], i2 = M[ri[2]][ci[2]];
  double m = a * (e * i2 - f * h) - b * (d * i2 - f * g) + c * (d * h - e * g);
  return (((rr + cc) & 1) ? -m : m);
}

// sums are UN-normalized: tot=Σw, sr=Σw*ref, ss=Σw*src, m9[c*3+d]=Σw*src_c*ref_d
__device__ inline void kabsch_from_sums(double tot, const double* sr, const double* ss,
                                        const double* m9, double* T12) {
  double den = tot + EPSD;
  double rc[3], sc[3];
  for (int c = 0; c < 3; ++c) { rc[c] = sr[c] / den; sc[c] = ss[c] / den; }
  double sb = tot / den;
  double H[3][3];
  for (int c = 0; c < 3; ++c)
    for (int d = 0; d < 3; ++d)
      H[c][d] = m9[c * 3 + d] / den - (2.0 - sb) * sc[c] * rc[d];
  if (tot < EPSD) {
    H[0][0] = 3.0; H[0][1] = 0.0; H[0][2] = 0.0;
    H[1][0] = 0.0; H[1][1] = 2.0; H[1][2] = 0.0;
    H[2][0] = 0.0; H[2][1] = 0.0; H[2][2] = 1.0;
  }
  double Sxx = H[0][0], Sxy = H[0][1], Sxz = H[0][2];
  double Syx = H[1][0], Syy = H[1][1], Syz = H[1][2];
  double Szx = H[2][0], Szy = H[2][1], Szz = H[2][2];
  double N[4][4] = {
    {Sxx + Syy + Szz, Syz - Szy,        Szx - Sxz,         Sxy - Syx},
    {Syz - Szy,       Sxx - Syy - Szz,  Sxy + Syx,         Szx + Sxz},
    {Szx - Sxz,       Sxy + Syx,       -Sxx + Syy - Szz,   Syz + Szy},
    {Sxy - Syx,       Szx + Sxz,        Syz + Szy,        -Sxx - Syy + Szz}};
  // ---- QCP largest eigenpair (trace(N)=0 => p(l)=l^4 + c2 l^2 + c1 l + c0) ----
  double fro2 = Sxx*Sxx + Sxy*Sxy + Sxz*Sxz + Syx*Syx + Syy*Syy + Syz*Syz +
                Szx*Szx + Szy*Szy + Szz*Szz;
  double c2 = -2.0 * fro2;
  double c1 = -8.0 * (Sxx * (Syy * Szz - Syz * Szy) -
                      Sxy * (Syx * Szz - Syz * Szx) +
                      Sxz * (Syx * Szy - Syy * Szx));
  double c0 = N[0][0] * cof3(N, 0, 0) + N[0][1] * cof3(N, 0, 1) +
              N[0][2] * cof3(N, 0, 2) + N[0][3] * cof3(N, 0, 3);
  // Gershgorin upper bound on lambda_max
  double lam = -1e300;
  for (int i = 0; i < 4; ++i) {
    double r = N[i][i];
    for (int j = 0; j < 4; ++j) if (j != i) r += fabs(N[i][j]);
    lam = fmax(lam, r);
  }
  // Newton from above: quadratic convergence; 20 iters >> enough from Gershgorin
  for (int it = 0; it < 20; ++it) {
    double l2 = lam * lam;
    double pv = ((l2 + c2) * lam + c1) * lam + c0;
    double dp = (4.0 * l2 + 2.0 * c2) * lam + c1;
    if (dp == 0.0) break;
    double d = pv / dp;
    lam -= d;
    if (fabs(d) <= 1e-14 * fmax(fabs(lam), 1e-30)) break;
  }
  // eigenvector via adjugate column of K = N - lam*I (largest diagonal cofactor)
  double K[4][4];
  for (int i = 0; i < 4; ++i)
    for (int j = 0; j < 4; ++j) K[i][j] = N[i][j];
  for (int i = 0; i < 4; ++i) K[i][i] -= lam;
  int jb = 0;
  double bestd = -1.0;
  for (int j = 0; j < 4; ++j) {
    double dj = fabs(cof3(K, j, j));
    if (dj > bestd) { bestd = dj; jb = j; }
  }
  double v[4];
  for (int i = 0; i < 4; ++i) v[i] = cof3(K, jb, i);
  double vn2 = v[0]*v[0] + v[1]*v[1] + v[2]*v[2] + v[3]*v[3];
  double scl = sqrt(fro2) + fabs(lam) + 1e-300;
  double thr = 1e-10 * scl * scl * scl;
  double q0, qx, qy, qz;
  if (vn2 > thr * thr) {
    double inv = 1.0 / sqrt(vn2);
    q0 = v[0] * inv; qx = v[1] * inv; qy = v[2] * inv; qz = v[3] * inv;
  } else {
    // fallback: full Jacobi (near-degenerate top eigenvalue)
    double A[4][4], V[4][4];
    for (int i = 0; i < 4; ++i)
      for (int j = 0; j < 4; ++j) A[i][j] = N[i][j];
    jacobi4(A, V);
    int kb = 0; double ev = A[0][0];
    for (int i = 1; i < 4; ++i) if (A[i][i] > ev) { ev = A[i][i]; kb = i; }
    double w0 = V[0][kb], w1 = V[1][kb], w2 = V[2][kb], w3 = V[3][kb];
    double nr = sqrt(w0*w0 + w1*w1 + w2*w2 + w3*w3);
    if (nr < 1e-300) { w0 = 1.0; w1 = w2 = w3 = 0.0; nr = 1.0; }
    q0 = w0 / nr; qx = w1 / nr; qy = w2 / nr; qz = w3 / nr;
  }
  double R[3][3];
  R[0][0] = q0*q0 + qx*qx - qy*qy - qz*qz; R[0][1] = 2.0*(qx*qy - q0*qz); R[0][2] = 2.0*(qx*qz + q0*qy);
  R[1][0] = 2.0*(qx*qy + q0*qz); R[1][1] = q0*q0 - qx*qx + qy*qy - qz*qz; R[1][2] = 2.0*(qy*qz - q0*qx);
  R[2][0] = 2.0*(qx*qz - q0*qy); R[2][1] = 2.0*(qy*qz + q0*qx); R[2][2] = q0*q0 - qx*qx - qy*qy + qz*qz;
  for (int c = 0; c < 3; ++c)
    for (int d = 0; d < 3; ++d) T12[c * 3 + d] = R[c][d];
  for (int c = 0; c < 3; ++c)
    T12[9 + c] = rc[c] - (R[c][0] * sc[0] + R[c][1] * sc[1] + R[c][2] * sc[2]);
}

// ---------------- fused: stage tile, thresholds, scan -> per-proposal corr list ----
__global__ __launch_bounds__(256, 2) void k_fused(
    const float* __restrict__ scores, const void* __restrict__ mref,
    const void* __restrict__ msrc, unsigned* __restrict__ ccnt,
    unsigned long long* __restrict__ clist) {
  const int p = blockIdx.x;
  const int tid = threadIdx.x;
  __shared__ float tile[128 * 132];
  __shared__ float colpart[2][NPT][3];
  __shared__ float rthr[NPT], cthr[NPT];
  __shared__ unsigned char lmr[NPT];
  __shared__ unsigned lcnt;
  __shared__ unsigned masku8_s;
  if (tid == 0) lcnt = 0;
  // per-block mask-dtype detect (i32 words are 0/1; u8 words pack 4 bools)
  if (tid < 64) {
    unsigned v = (tid < 32) ? ((const unsigned*)mref)[p * 32 + tid]
                            : ((const unsigned*)msrc)[p * 32 + (tid - 32)];
    unsigned long long any = __ballot(v > 1u);
    if (tid == 0) masku8_s = any ? 1u : 0u;
  }
  // stage the 128x128 tile: 16 independent coalesced float4 loads
  {
    const float4* S4 = (const float4*)(scores + (size_t)p * NN2);
    float4 vv[16];
#pragma unroll
    for (int s = 0; s < 16; ++s)
      vv[s] = S4[s * 256 + tid];
#pragma unroll
    for (int s = 0; s < 16; ++s) {
      int flat = (s * 256 + tid) * 4;
      int r = flat >> 7, c = flat & 127;
      *(float4*)&tile[r * 132 + c] = vv[s];
    }
  }
  __syncthreads();
  const unsigned maskU8 = masku8_s;
  if (tid < NPT)
    lmr[tid] = maskU8 ? (((const unsigned char*)mref)[p * NPT + tid] != 0)
                      : (((const int*)mref)[p * NPT + tid] != 0);
  const int col = tid & 127;
  const int half = tid >> 7;
  const bool msj = maskU8 ? (((const unsigned char*)msrc)[p * NPT + col] != 0)
                          : (((const int*)msrc)[p * NPT + col] != 0);
  // row top-3: 8 lanes/row, b128 reads, shuffle-xor merge
  for (int rb = 0; rb < 4; ++rb) {
    int r = rb * 32 + (tid >> 3);
    int o = tid & 7;
    float a = NEGF, b = NEGF, c = NEGF;
    const float4* tr = (const float4*)&tile[r * 132 + o * 16];
#pragma unroll
    for (int k = 0; k < 4; ++k) {
      float4 q = tr[k];
      top3_upd(q.x, a, b, c); top3_upd(q.y, a, b, c);
      top3_upd(q.z, a, b, c); top3_upd(q.w, a, b, c);
    }
#pragma unroll
    for (int m = 1; m < 8; m <<= 1) {
      float pa = __shfl_xor(a, m, 64), pb = __shfl_xor(b, m, 64), pc = __shfl_xor(c, m, 64);
      merge3(a, b, c, pa, pb, pc);
    }
    if (o == 0) rthr[r] = c;
  }
  // col top-3: consecutive-lane conflict-free LDS reads
  {
    float a = NEGF, b = NEGF, c = NEGF;
    const float* tc = tile + (half * 64) * 132 + col;
#pragma unroll 8
    for (int r = 0; r < 64; ++r)
      top3_upd(tc[r * 132], a, b, c);
    colpart[half][col][0] = a; colpart[half][col][1] = b; colpart[half][col][2] = c;
  }
  __syncthreads();
  if (tid < NPT) {
    float a = colpart[0][tid][0], b = colpart[0][tid][1], c = colpart[0][tid][2];
    merge3(a, b, c, colpart[1][tid][0], colpart[1][tid][1], colpart[1][tid][2]);
    cthr[tid] = c;
  }
  __syncthreads();
  // corr scan: append to this proposal's private global list (no global atomics)
  {
    const float cth = cthr[col];
    const float* tc = tile + (half * 64) * 132 + col;
#pragma unroll 4
    for (int it = 0; it < 64; ++it) {
      float v = tc[it * 132];
      int i = half * 64 + it;
      if (msj && v >= cth && v >= rthr[i] && lmr[i] && (expf(v) > THRESH)) {
        unsigned pos = atomicAdd(&lcnt, 1u);   // LDS atomic only
        if (pos < MAXCPB) {
          unsigned long long key =
              (((unsigned long long)(~enc_f(v))) << 32) |
              (unsigned long long)(unsigned)(p * NN2 + i * NPT + col);
          clist[(size_t)p * MAXCPB + pos] = key;
        }
      }
    }
  }
  __syncthreads();
  if (tid == 0) ccnt[p] = (lcnt < MAXCPB) ? lcnt : MAXCPB;
}

// ---------------- partial histograms: 64 blocks x 16 proposals, no atomics out ----
__global__ __launch_bounds__(256) void k_hist(
    const unsigned* __restrict__ ccnt, const unsigned long long* __restrict__ clist,
    unsigned* __restrict__ phist) {
  __shared__ unsigned lh[4096];
  const int b = blockIdx.x, tid = threadIdx.x;
  for (int i = tid; i < 4096; i += 256) lh[i] = 0;
  __syncthreads();
  for (int q = 0; q < 16; ++q) {
    const int p = b * 16 + q;
    const unsigned cnt = min(ccnt[p], (unsigned)MAXCPB);
    const unsigned long long* my = clist + (size_t)p * MAXCPB;
    for (unsigned t = tid; t < cnt; t += 256)
      atomicAdd(&lh[(unsigned)(my[t] >> 52)], 1u);
  }
  __syncthreads();
  for (int i = tid; i < 4096; i += 256) phist[b * 4096 + i] = lh[i];
}

// ---------------- reduce partials, find cutoff bin ----------------
__global__ __launch_bounds__(1024) void k_cut(const unsigned* __restrict__ phist,
                                              unsigned* __restrict__ hdr) {
  __shared__ unsigned s[1024];
  __shared__ unsigned cb_s;
  const int tid = threadIdx.x;
  if (tid == 0) cb_s = 4095u;
  uint4 acc = make_uint4(0, 0, 0, 0);
  const uint4* ph4 = (const uint4*)phist;
#pragma unroll 4
  for (int b = 0; b < 64; ++b) {
    uint4 h = ph4[b * 1024 + tid];
    acc.x += h.x; acc.y += h.y; acc.z += h.z; acc.w += h.w;
  }
  s[tid] = acc.x + acc.y + acc.z + acc.w;
  __syncthreads();
  for (int off = 1; off < 1024; off <<= 1) {
    unsigned v = s[tid];
    unsigned a = (tid >= off) ? s[tid - off] : 0u;
    __syncthreads();
    s[tid] = v + a;
    __syncthreads();
  }
  {
    unsigned pre = (tid > 0) ? s[tid - 1] : 0u;
    unsigned tot4 = acc.x + acc.y + acc.z + acc.w;
    if (pre < MAXC && pre + tot4 >= MAXC) {   // unique thread
      unsigned c0 = pre + acc.x, c1 = c0 + acc.y, c2 = c1 + acc.z;
      cb_s = (c0 >= MAXC) ? tid * 4 : (c1 >= MAXC) ? tid * 4 + 1
           : (c2 >= MAXC) ? tid * 4 + 2 : tid * 4 + 3;
    }
  }
  __syncthreads();
  if (tid == 0) {
    hdr[0] = s[1023];   // total corr count
    hdr[1] = 0u;        // sel counter (for k_gather)
    hdr[2] = cb_s;      // cutoff bin
  }
}

// ---------------- gather survivors (wave-aggregated appends) ----------------
__global__ __launch_bounds__(256) void k_gather(
    const unsigned* __restrict__ ccnt, const unsigned long long* __restrict__ clist,
    unsigned* __restrict__ hdr, unsigned long long* __restrict__ sel) {
  const int b = blockIdx.x, tid = threadIdx.x, lane = tid & 63;
  const unsigned cut = hdr[2];
  for (int q = 0; q < 16; ++q) {
    const int p = b * 16 + q;
    const unsigned cnt = min(ccnt[p], (unsigned)MAXCPB);
    const unsigned long long* my = clist + (size_t)p * MAXCPB;
    for (unsigned t0 = 0; t0 < cnt; t0 += 256) {
      unsigned t = t0 + tid;
      unsigned long long key = 0;
      bool take = false;
      if (t < cnt) {
        key = my[t];
        take = ((unsigned)(key >> 52)) <= cut;
      }
      unsigned long long mb = __ballot(take);
      if (mb) {
        int leader = __ffsll((unsigned long long)mb) - 1;
        unsigned base = 0;
        if (lane == leader) base = atomicAdd(&hdr[1], (unsigned)__popcll(mb));
        base = __shfl(base, leader, 64);
        if (take) {
          unsigned pos = base + (unsigned)__popcll(mb & ((1ull << lane) - 1ull));
          if (pos < SELCAP) sel[pos] = key;
        }
      }
    }
  }
}

// ---- sort (wave-synchronous LDS bitonic, pair-indexed) + write outputs/pool ----
__global__ __launch_bounds__(1024) void k_sortout(
    const unsigned long long* __restrict__ sel, const unsigned* __restrict__ hdr,
    const float* __restrict__ refp, const float* __restrict__ srcp,
    float* __restrict__ pool, float* __restrict__ out) {
  __shared__ unsigned long long keys[4096];
  const int tid = threadIdx.x;
  const unsigned sc = min(hdr[1], SELCAP);
  const unsigned n2 = (sc <= 2048u) ? 2048u : 4096u;
  for (unsigned t = tid; t < n2; t += 1024)
    keys[t] = (t < sc) ? sel[t] : 0xFFFFFFFFFFFFFFFFull;
  __syncthreads();
  const unsigned chunk = n2 >> 4;          // 16 waves, one aligned chunk each
  const unsigned w = tid >> 6, lane = tid & 63;
  const unsigned base = w * chunk;
  for (unsigned k = 2; k <= n2; k <<= 1) {
    unsigned j = k >> 1;
    // block-wide passes while pairs cross chunk boundaries
    for (; j >= chunk; j >>= 1) {
      for (unsigned q = tid; q < (n2 >> 1); q += 1024) {
        unsigned t = ((q & ~(j - 1u)) << 1) | (q & (j - 1u));
        unsigned u = t | j;
        bool up = ((t & k) == 0u);
        unsigned long long A = keys[t], B = keys[u];
        if (up ? (A > B) : (A < B)) { keys[t] = B; keys[u] = A; }
      }
      __syncthreads();
    }
    // wave-local passes: j < chunk, each wave owns its aligned chunk
    for (; j; j >>= 1) {
      for (unsigned q = lane; q < (chunk >> 1); q += 64) {
        unsigned lt = ((q & ~(j - 1u)) << 1) | (q & (j - 1u));
        unsigned t = base + lt;
        unsigned u = t | j;                // stays inside the chunk
        bool up = ((t & k) == 0u);
        unsigned long long A = keys[t], B = keys[u];
        if (up ? (A > B) : (A < B)) { keys[t] = B; keys[u] = A; }
      }
      // no barrier: same-wave LDS ops execute in order; pairs are disjoint
    }
    __syncthreads();
  }
  const unsigned stotal = hdr[0];
  const unsigned nreal = (stotal < MAXC) ? stotal : MAXC;
  for (int mm = tid; mm < MAXC; mm += 1024) {
    unsigned flat; float score; bool real = ((unsigned)mm < nreal);
    if (real) {
      unsigned long long key = keys[mm];
      flat = (unsigned)(key & 0xFFFFFFFFull);
      score = expf(dec_f(~(unsigned)(key >> 32)));
    } else {
      flat = (unsigned)mm;
      score = 0.f;
    }
    unsigned p = flat >> 14, rem = flat & 16383u, i = rem >> 7, j = rem & 127u;
    float rx = refp[((size_t)p * NPT + i) * 3 + 0];
    float ry = refp[((size_t)p * NPT + i) * 3 + 1];
    float rz = refp[((size_t)p * NPT + i) * 3 + 2];
    float sx = srcp[((size_t)p * NPT + j) * 3 + 0];
    float sy = srcp[((size_t)p * NPT + j) * 3 + 1];
    float sz = srcp[((size_t)p * NPT + j) * 3 + 2];
    out[mm * 3 + 0] = rx; out[mm * 3 + 1] = ry; out[mm * 3 + 2] = rz;
    out[4500 + mm * 3 + 0] = sx; out[4500 + mm * 3 + 1] = sy; out[4500 + mm * 3 + 2] = sz;
    out[9000 + mm] = score;
    pool[mm * 3 + 0] = rx; pool[mm * 3 + 1] = ry; pool[mm * 3 + 2] = rz;
    pool[4500 + mm * 3 + 0] = sx; pool[4500 + mm * 3 + 1] = sy; pool[4500 + mm * 3 + 2] = sz;
    float pad = real ? 0.f : 1e6f;
    pool[9000 + mm * 3 + 0] = sx + pad;
    pool[9000 + mm * 3 + 1] = sy + pad;
    pool[9000 + mm * 3 + 2] = sz + pad;
    pool[13500 + mm] = score;
  }
}

// ---------------- per-proposal: stats from clist + Kabsch + inlier count ----------
__global__ __launch_bounds__(256) void k_evalT(
    const unsigned* __restrict__ ccnt, const unsigned long long* __restrict__ clist,
    const float* __restrict__ refp, const float* __restrict__ srcp,
    const float* __restrict__ pool, double* __restrict__ trans,
    int* __restrict__ icount) {
  const int p = blockIdx.x, tid = threadIdx.x, lane = tid & 63;
  __shared__ double red[4][16];
  __shared__ double Ts[12];
  __shared__ int redc[4];
  const unsigned cnt = min(ccnt[p], (unsigned)MAXCPB);
  double tot = 0, sr0 = 0, sr1 = 0, sr2 = 0, ss0 = 0, ss1 = 0, ss2 = 0;
  double m00 = 0, m01 = 0, m02 = 0, m10 = 0, m11 = 0, m12 = 0, m20 = 0, m21 = 0, m22 = 0;
  for (unsigned t = tid; t < cnt; t += 256) {
    unsigned long long key = clist[(size_t)p * MAXCPB + t];
    unsigned flat = (unsigned)(key & 0xFFFFFFFFull);
    unsigned rem = flat & 16383u, i = rem >> 7, j = rem & 127u;
    double w = (double)expf(dec_f(~(unsigned)(key >> 32)));
    double rx = refp[((size_t)p * NPT + i) * 3 + 0];
    double ry = refp[((size_t)p * NPT + i) * 3 + 1];
    double rz = refp[((size_t)p * NPT + i) * 3 + 2];
    double sx = srcp[((size_t)p * NPT + j) * 3 + 0];
    double sy = srcp[((size_t)p * NPT + j) * 3 + 1];
    double sz = srcp[((size_t)p * NPT + j) * 3 + 2];
    tot += w;
    sr0 += w * rx; sr1 += w * ry; sr2 += w * rz;
    ss0 += w * sx; ss1 += w * sy; ss2 += w * sz;
    double wsx = w * sx, wsy = w * sy, wsz = w * sz;
    m00 += wsx * rx; m01 += wsx * ry; m02 += wsx * rz;
    m10 += wsy * rx; m11 += wsy * ry; m12 += wsy * rz;
    m20 += wsz * rx; m21 += wsz * ry; m22 += wsz * rz;
  }
  double vals[16] = {tot, sr0, sr1, sr2, ss0, ss1, ss2,
                     m00, m01, m02, m10, m11, m12, m20, m21, m22};
#pragma unroll
  for (int k = 0; k < 16; ++k) {
    double x = vals[k];
    for (int o = 32; o; o >>= 1) x += __shfl_down(x, o, 64);
    if (lane == 0) red[tid >> 6][k] = x;
  }
  __syncthreads();
  if (tid == 0) {
    double s16[16];
    for (int k = 0; k < 16; ++k)
      s16[k] = red[0][k] + red[1][k] + red[2][k] + red[3][k];
    kabsch_from_sums(s16[0], s16 + 1, s16 + 4, s16 + 7, Ts);
    for (int k = 0; k < 12; ++k) trans[p * 12 + k] = Ts[k];
  }
  __syncthreads();
  double R00 = Ts[0], R01 = Ts[1], R02 = Ts[2], R10 = Ts[3], R11 = Ts[4], R12 = Ts[5];
  double R20 = Ts[6], R21 = Ts[7], R22 = Ts[8], t0 = Ts[9], t1 = Ts[10], t2 = Ts[11];
  const float* pr = pool;
  const float* pe = pool + 9000;
  int c = 0;
  for (int mm = tid; mm < MAXC; mm += 256) {
    double ex = pe[mm * 3], ey = pe[mm * 3 + 1], ez = pe[mm * 3 + 2];
    double ax = R00 * ex + R01 * ey + R02 * ez + t0;
    double ay = R10 * ex + R11 * ey + R12 * ez + t1;
    double az = R20 * ex + R21 * ey + R22 * ez + t2;
    double dx = pr[mm * 3] - ax, dy = pr[mm * 3 + 1] - ay, dz = pr[mm * 3 + 2] - az;
    if (dx * dx + dy * dy + dz * dz < RRD) ++c;
  }
  for (int o = 32; o; o >>= 1) c += __shfl_down(c, o, 64);
  if (lane == 0) redc[tid >> 6] = c;
  __syncthreads();
  if (tid == 0) {
    int tc = redc[0] + redc[1] + redc[2] + redc[3];
    icount[p] = (cnt >= 3u) ? tc : -1;
  }
}

// -------- argmax + iterative refinement: ONE WAVE, no barriers, no LDS --------
__global__ __launch_bounds__(64, 1) void k_refine(const double* __restrict__ trans,
                                                  const int* __restrict__ icount,
                                                  const float* __restrict__ pool,
                                                  float* __restrict__ out) {
  const int lane = threadIdx.x;
  // argmax (first-max semantics: strict > keeps lowest index; merges compare idx)
  int bc = -2147483647, bi = 0;
  for (int idx = lane; idx < PP; idx += 64) {
    int c = icount[idx];
    if (c > bc) { bc = c; bi = idx; }
  }
  for (int o = 32; o; o >>= 1) {
    int c2 = __shfl_down(bc, o, 64);
    int i2 = __shfl_down(bi, o, 64);
    if (c2 > bc || (c2 == bc && i2 < bi)) { bc = c2; bi = i2; }
  }
  bi = __shfl(bi, 0, 64);
  double T[12];
#pragma unroll
  for (int k = 0; k < 12; ++k) T[k] = trans[bi * 12 + k];  // all lanes same loads
  const float* pr = pool;
  const float* ps = pool + 4500;
  const float* pe = pool + 9000;
  const float* pw = pool + 13500;
  for (int iter = 0; iter < 5; ++iter) {
    double R00 = T[0], R01 = T[1], R02 = T[2], R10 = T[3], R11 = T[4], R12 = T[5];
    double R20 = T[6], R21 = T[7], R22 = T[8], t0 = T[9], t1 = T[10], t2 = T[11];
    double acc[16];
#pragma unroll
    for (int k = 0; k < 16; ++k) acc[k] = 0.0;
    for (int mm = lane; mm < MAXC; mm += 64) {
      double ex = pe[mm * 3], ey = pe[mm * 3 + 1], ez = pe[mm * 3 + 2];
      double ax = R00 * ex + R01 * ey + R02 * ez + t0;
      double ay = R10 * ex + R11 * ey + R12 * ez + t1;
      double az = R20 * ex + R21 * ey + R22 * ez + t2;
      double rx = pr[mm * 3], ry = pr[mm * 3 + 1], rz = pr[mm * 3 + 2];
      double dx = rx - ax, dy = ry - ay, dz = rz - az;
      if (dx * dx + dy * dy + dz * dz < RRD) {
        double w = (double)pw[mm];
        double sx = ps[mm * 3], sy = ps[mm * 3 + 1], sz = ps[mm * 3 + 2];
        acc[0] += w;
        acc[1] += w * rx; acc[2] += w * ry; acc[3] += w * rz;
        acc[4] += w * sx; acc[5] += w * sy; acc[6] += w * sz;
        double wsx = w * sx, wsy = w * sy, wsz = w * sz;
        acc[7]  += wsx * rx; acc[8]  += wsx * ry; acc[9]  += wsx * rz;
        acc[10] += wsy * rx; acc[11] += wsy * ry; acc[12] += wsy * rz;
        acc[13] += wsz * rx; acc[14] += wsz * ry; acc[15] += wsz * rz;
      }
    }
#pragma unroll
    for (int k = 0; k < 16; ++k)
      for (int o = 32; o; o >>= 1) acc[k] += __shfl_down(acc[k], o, 64);
    if (lane == 0)
      kabsch_from_sums(acc[0], acc + 1, acc + 4, acc + 7, T);
#pragma unroll
    for (int k = 0; k < 12; ++k) T[k] = __shfl(T[k], 0, 64);  // wave broadcast
  }
  if (lane == 0) {
    out[10500 + 0]  = (float)T[0]; out[10500 + 1]  = (float)T[1];
    out[10500 + 2]  = (float)T[2]; out[10500 + 3]  = (float)T[9];
    out[10500 + 4]  = (float)T[3]; out[10500 + 5]  = (float)T[4];
    out[10500 + 6]  = (float)T[5]; out[10500 + 7]  = (float)T[10];
    out[10500 + 8]  = (float)T[6]; out[10500 + 9]  = (float)T[7];
    out[10500 + 10] = (float)T[8]; out[10500 + 11] = (float)T[11];
    out[10500 + 12] = 0.f; out[10500 + 13] = 0.f;
    out[10500 + 14] = 0.f; out[10500 + 15] = 1.f;
  }
}

extern "C" void kernel_launch(void* const* d_in, const int* in_sizes, int n_in,
                              void* d_out, int out_size, void* d_ws, size_t ws_size,
                              hipStream_t stream) {
  const float* refp = (const float*)d_in[0];
  const float* srcp = (const float*)d_in[1];
  const void* mref = d_in[2];
  const void* msrc = d_in[3];
  const float* scores = (const float*)d_in[4];
  float* out = (float*)d_out;
  char* ws = (char*)d_ws;
  unsigned* ccnt = (unsigned*)(ws + OFF_CCNT);
  int* icount = (int*)(ws + OFF_ICNT);
  double* trans = (double*)(ws + OFF_TRANS);
  float* pool = (float*)(ws + OFF_POOL);
  unsigned* hdr = (unsigned*)(ws + OFF_HDR);
  unsigned long long* sel = (unsigned long long*)(ws + OFF_SEL);
  unsigned* phist = (unsigned*)(ws + OFF_PHIST);
  unsigned long long* clist = (unsigned long long*)(ws + OFF_CLIST);

  k_fused<<<PP, 256, 0, stream>>>(scores, mref, msrc, ccnt, clist);
  k_hist<<<64, 256, 0, stream>>>(ccnt, clist, phist);
  k_cut<<<1, 1024, 0, stream>>>(phist, hdr);
  k_gather<<<64, 256, 0, stream>>>(ccnt, clist, hdr, sel);
  k_sortout<<<1, 1024, 0, stream>>>(sel, hdr, refp, srcp, pool, out);
  k_evalT<<<PP, 256, 0, stream>>>(ccnt, clist, refp, srcp, pool, trans, icount);
  k_refine<<<1, 64, 0, stream>>>(trans, icount, pool, out);
}

// Round 10
// 320.954 us; speedup vs baseline: 1.0014x; 1.0014x over previous
//
#include <hip/hip_runtime.h>
#include <math.h>

#define PP    1024
#define NPT   128
#define NN2   16384
#define THRESH 0.05f
#define MAXC  1500
#define EPSD  1e-5
#define RRD   (0.1*0.1)
#define NEGF  -3.0e38f
#define MAXCPB 384      // mutual-top3 per proposal is mathematically <= 3*128
#define SELCAP 4096u

// ---- workspace byte offsets (everything written before read; no memsets) ----
#define OFF_CCNT  0          // u32[1024]                  -> 4096
#define OFF_ICNT  4096       // int[1024]                  -> 8192
#define OFF_TRANS 8192       // double[1024*12]            -> 106496
#define OFF_POOL  106496     // float[15000]               -> 166496
#define OFF_HDR   166496     // u32[16]: 0=total 1=selCnt 2=cutbin -> 166560
#define OFF_SEL   166560     // u64[4096]                  -> 199328
#define OFF_PHIST 199328     // u32[64*4096]               -> 1247904
#define OFF_CLIST 1247904    // u64[1024*384]              -> 4393632

// ---------------- branchless top-3 helpers ----------------
__device__ inline void top3_upd(float v, float& a, float& b, float& c) {
  float m1 = fminf(a, v);
  a = fmaxf(a, v);
  float m2 = fminf(b, m1);
  b = fmaxf(b, m1);
  c = fmaxf(c, m2);
}
__device__ inline void merge3(float& a, float& b, float& c, float x0, float x1, float x2) {
  float z0 = fmaxf(a, x0);
  float z1 = fmaxf(fminf(a, x0), fmaxf(b, x1));
  float z2 = fmaxf(fmaxf(c, x2), fmaxf(fminf(b, x0), fminf(a, x1)));
  a = z0; b = z1; c = z2;
}

// sortable float encoding (enc ascending == v ascending)
__device__ inline unsigned enc_f(float v) {
  unsigned b = __float_as_uint(v);
  return (b & 0x80000000u) ? ~b : (b | 0x80000000u);
}
__device__ inline float dec_f(unsigned enc) {
  unsigned b = (enc & 0x80000000u) ? (enc ^ 0x80000000u) : ~enc;
  return __uint_as_float(b);
}

// ---------------- Jacobi fallback (rare: near-degenerate eigenvalue gap) --------
__device__ void jacobi4(double A[4][4], double V[4][4]) {
  for (int i = 0; i < 4; ++i)
    for (int j = 0; j < 4; ++j) V[i][j] = (i == j) ? 1.0 : 0.0;
  const int PI_[6] = {0, 0, 0, 1, 1, 2};
  const int QI_[6] = {1, 2, 3, 2, 3, 3};
  for (int sweep = 0; sweep < 30; ++sweep) {
    double off = fabs(A[0][1]) + fabs(A[0][2]) + fabs(A[0][3]) +
                 fabs(A[1][2]) + fabs(A[1][3]) + fabs(A[2][3]);
    double dia = fabs(A[0][0]) + fabs(A[1][1]) + fabs(A[2][2]) + fabs(A[3][3]);
    if (off <= 1e-14 * (dia + 1e-300)) break;
    for (int r = 0; r < 6; ++r) {
      int p = PI_[r], q = QI_[r];
      double apq = A[p][q];
      if (fabs(apq) <= 1e-18 * (fabs(A[p][p]) + fabs(A[q][q]) + 1e-300)) continue;
      double theta = (A[q][q] - A[p][p]) / (2.0 * apq);
      double t = ((theta >= 0.0) ? 1.0 : -1.0) / (fabs(theta) + sqrt(1.0 + theta * theta));
      double c = 1.0 / sqrt(1.0 + t * t);
      double s = t * c;
      for (int k = 0; k < 4; ++k) {
        double akp = A[k][p], akq = A[k][q];
        A[k][p] = c * akp - s * akq;
        A[k][q] = s * akp + c * akq;
      }
      for (int k = 0; k < 4; ++k) {
        double apk = A[p][k], aqk = A[q][k];
        A[p][k] = c * apk - s * aqk;
        A[q][k] = s * apk + c * aqk;
      }
      for (int k = 0; k < 4; ++k) {
        double vkp = V[k][p], vkq = V[k][q];
        V[k][p] = c * vkp - s * vkq;
        V[k][q] = s * vkp + c * vkq;
      }
    }
  }
}

// sums are UN-normalized: tot=Σw, sr=Σw*ref, ss=Σw*src, m9[c*3+d]=Σw*src_c*ref_d
// FULLY SCALARIZED: no dynamically-indexed private arrays -> stays in registers.
__device__ inline void kabsch_from_sums(double tot, const double* sr, const double* ss,
                                        const double* m9, double* T12) {
  double den = tot + EPSD;
  double rcx = sr[0] / den, rcy = sr[1] / den, rcz = sr[2] / den;
  double scx = ss[0] / den, scy = ss[1] / den, scz = ss[2] / den;
  double f = 2.0 - tot / den;
  double Sxx = m9[0] / den - f * scx * rcx;
  double Sxy = m9[1] / den - f * scx * rcy;
  double Sxz = m9[2] / den - f * scx * rcz;
  double Syx = m9[3] / den - f * scy * rcx;
  double Syy = m9[4] / den - f * scy * rcy;
  double Syz = m9[5] / den - f * scy * rcz;
  double Szx = m9[6] / den - f * scz * rcx;
  double Szy = m9[7] / den - f * scz * rcy;
  double Szz = m9[8] / den - f * scz * rcz;
  if (tot < EPSD) {
    Sxx = 3.0; Sxy = 0.0; Sxz = 0.0;
    Syx = 0.0; Syy = 2.0; Syz = 0.0;
    Szx = 0.0; Szy = 0.0; Szz = 1.0;
  }
  // symmetric N (10 unique entries)
  double n00 = Sxx + Syy + Szz, n01 = Syz - Szy, n02 = Szx - Sxz, n03 = Sxy - Syx;
  double n11 = Sxx - Syy - Szz, n12 = Sxy + Syx, n13 = Szx + Sxz;
  double n22 = -Sxx + Syy - Szz, n23 = Syz + Szy;
  double n33 = -Sxx - Syy + Szz;
  // char poly: l^4 + c2 l^2 + c1 l + c0  (trace(N)=0)
  double fro2 = Sxx*Sxx + Sxy*Sxy + Sxz*Sxz + Syx*Syx + Syy*Syy + Syz*Syz +
                Szx*Szx + Szy*Szy + Szz*Szz;
  double c2 = -2.0 * fro2;
  double c1 = -8.0 * (Sxx * (Syy * Szz - Syz * Szy) -
                      Sxy * (Syx * Szz - Syz * Szx) +
                      Sxz * (Syx * Szy - Syy * Szx));
  // det(N) via 2x2-minor expansion (all named scalars)
  double s0 = n00 * n11 - n01 * n01;
  double s1 = n00 * n12 - n02 * n01;
  double s2 = n00 * n13 - n03 * n01;
  double s3 = n01 * n12 - n02 * n11;
  double s4 = n01 * n13 - n03 * n11;
  double s5 = n02 * n13 - n03 * n12;
  double t0 = n02 * n13 - n12 * n03;
  double t1 = n02 * n23 - n22 * n03;
  double t2 = n02 * n33 - n23 * n03;
  double t3 = n12 * n23 - n22 * n13;
  double t4 = n12 * n33 - n23 * n13;
  double t5 = n22 * n33 - n23 * n23;
  double c0 = s0 * t5 - s1 * t4 + s2 * t3 + s3 * t2 - s4 * t1 + s5 * t0;
  // Gershgorin upper bound
  double g0 = n00 + fabs(n01) + fabs(n02) + fabs(n03);
  double g1 = n11 + fabs(n01) + fabs(n12) + fabs(n13);
  double g2 = n22 + fabs(n02) + fabs(n12) + fabs(n23);
  double g3 = n33 + fabs(n03) + fabs(n13) + fabs(n23);
  double lam = fmax(fmax(g0, g1), fmax(g2, g3));
  // Newton from above (monotone; quadratic; <=20 iters)
  for (int it = 0; it < 20; ++it) {
    double l2 = lam * lam;
    double pv = ((l2 + c2) * lam + c1) * lam + c0;
    double dp = (4.0 * l2 + 2.0 * c2) * lam + c1;
    if (dp == 0.0) break;
    double d = pv / dp;
    lam -= d;
    if (fabs(d) <= 1e-14 * fmax(fabs(lam), 1e-30)) break;
  }
  // K = N - lam I, symmetric; adjugate via explicit 16-term block (constant indices)
  double e0 = n00 - lam, e1 = n01,       e2 = n02,       e3 = n03;
  double e4 = n01,       e5 = n11 - lam, e6 = n12,       e7 = n13;
  double e8 = n02,       e9 = n12,       e10 = n22 - lam, e11 = n23;
  double e12 = n03,      e13 = n13,      e14 = n23,      e15 = n33 - lam;
  double i0  =  e5*e10*e15 - e5*e11*e14 - e9*e6*e15 + e9*e7*e14 + e13*e6*e11 - e13*e7*e10;
  double i4  = -e4*e10*e15 + e4*e11*e14 + e8*e6*e15 - e8*e7*e14 - e12*e6*e11 + e12*e7*e10;
  double i8  =  e4*e9*e15  - e4*e11*e13 - e8*e5*e15 + e8*e7*e13 + e12*e5*e11 - e12*e7*e9;
  double i12 = -e4*e9*e14  + e4*e10*e13 + e8*e5*e14 - e8*e6*e13 - e12*e5*e10 + e12*e6*e9;
  double i1  = -e1*e10*e15 + e1*e11*e14 + e9*e2*e15 - e9*e3*e14 - e13*e2*e11 + e13*e3*e10;
  double i5  =  e0*e10*e15 - e0*e11*e14 - e8*e2*e15 + e8*e3*e14 + e12*e2*e11 - e12*e3*e10;
  double i9  = -e0*e9*e15  + e0*e11*e13 + e8*e1*e15 - e8*e3*e13 - e12*e1*e11 + e12*e3*e9;
  double i13 =  e0*e9*e14  - e0*e10*e13 - e8*e1*e14 + e8*e2*e13 + e12*e1*e10 - e12*e2*e9;
  double i2  =  e1*e6*e15  - e1*e7*e14  - e5*e2*e15 + e5*e3*e14 + e13*e2*e7  - e13*e3*e6;
  double i6  = -e0*e6*e15  + e0*e7*e14  + e4*e2*e15 - e4*e3*e14 - e12*e2*e7  + e12*e3*e6;
  double i10 =  e0*e5*e15  - e0*e7*e13  - e4*e1*e15 + e4*e3*e13 + e12*e1*e7  - e12*e3*e5;
  double i14 = -e0*e5*e14  + e0*e6*e13  + e4*e1*e14 - e4*e2*e13 - e12*e1*e6  + e12*e2*e5;
  double i3  = -e1*e6*e11  + e1*e7*e10  + e5*e2*e11 - e5*e3*e10 - e9*e2*e7   + e9*e3*e6;
  double i7  =  e0*e6*e11  - e0*e7*e10  - e4*e2*e11 + e4*e3*e10 + e8*e2*e7   - e8*e3*e6;
  double i11 = -e0*e5*e11  + e0*e7*e9   + e4*e1*e11 - e4*e3*e9  - e8*e1*e7   + e8*e3*e5;
  double i15 =  e0*e5*e10  - e0*e6*e9   - e4*e1*e10 + e4*e2*e9  + e8*e1*e6   - e8*e2*e5;
  // pick the adjugate row with the largest diagonal entry (same criterion as before)
  double d0 = fabs(i0), d1 = fabs(i5), d2 = fabs(i10), d3 = fabs(i15);
  double v0, v1, v2, v3;
  if (d0 >= d1 && d0 >= d2 && d0 >= d3)      { v0 = i0;  v1 = i1;  v2 = i2;  v3 = i3;  }
  else if (d1 >= d2 && d1 >= d3)             { v0 = i4;  v1 = i5;  v2 = i6;  v3 = i7;  }
  else if (d2 >= d3)                         { v0 = i8;  v1 = i9;  v2 = i10; v3 = i11; }
  else                                       { v0 = i12; v1 = i13; v2 = i14; v3 = i15; }
  double vn2 = v0 * v0 + v1 * v1 + v2 * v2 + v3 * v3;
  double scl = sqrt(fro2) + fabs(lam) + 1e-300;
  double thr = 1e-10 * scl * scl * scl;
  double q0, qx, qy, qz;
  if (vn2 > thr * thr) {
    double inv = 1.0 / sqrt(vn2);
    q0 = v0 * inv; qx = v1 * inv; qy = v2 * inv; qz = v3 * inv;
  } else {
    // rare fallback: full Jacobi on reconstructed N
    double A[4][4] = {{n00, n01, n02, n03}, {n01, n11, n12, n13},
                      {n02, n12, n22, n23}, {n03, n13, n23, n33}};
    double V[4][4];
    jacobi4(A, V);
    int kb = 0; double ev = A[0][0];
    for (int i = 1; i < 4; ++i) if (A[i][i] > ev) { ev = A[i][i]; kb = i; }
    double w0 = V[0][kb], w1 = V[1][kb], w2 = V[2][kb], w3 = V[3][kb];
    double nr = sqrt(w0 * w0 + w1 * w1 + w2 * w2 + w3 * w3);
    if (nr < 1e-300) { w0 = 1.0; w1 = w2 = w3 = 0.0; nr = 1.0; }
    q0 = w0 / nr; qx = w1 / nr; qy = w2 / nr; qz = w3 / nr;
  }
  double R00 = q0*q0 + qx*qx - qy*qy - qz*qz, R01 = 2.0*(qx*qy - q0*qz), R02 = 2.0*(qx*qz + q0*qy);
  double R10 = 2.0*(qx*qy + q0*qz), R11 = q0*q0 - qx*qx + qy*qy - qz*qz, R12 = 2.0*(qy*qz - q0*qx);
  double R20 = 2.0*(qx*qz - q0*qy), R21 = 2.0*(qy*qz + q0*qx), R22 = q0*q0 - qx*qx - qy*qy + qz*qz;
  T12[0] = R00; T12[1] = R01; T12[2] = R02;
  T12[3] = R10; T12[4] = R11; T12[5] = R12;
  T12[6] = R20; T12[7] = R21; T12[8] = R22;
  T12[9]  = rcx - (R00 * scx + R01 * scy + R02 * scz);
  T12[10] = rcy - (R10 * scx + R11 * scy + R12 * scz);
  T12[11] = rcz - (R20 * scx + R21 * scy + R22 * scz);
}

// ---------------- fused: stage tile, thresholds, scan -> per-proposal corr list ----
__global__ __launch_bounds__(256, 2) void k_fused(
    const float* __restrict__ scores, const void* __restrict__ mref,
    const void* __restrict__ msrc, unsigned* __restrict__ ccnt,
    unsigned long long* __restrict__ clist) {
  const int p = blockIdx.x;
  const int tid = threadIdx.x;
  __shared__ float tile[128 * 132];
  __shared__ float colpart[2][NPT][3];
  __shared__ float rthr[NPT], cthr[NPT];
  __shared__ unsigned char lmr[NPT];
  __shared__ unsigned lcnt;
  __shared__ unsigned masku8_s;
  if (tid == 0) lcnt = 0;
  // per-block mask-dtype detect (i32 words are 0/1; u8 words pack 4 bools)
  if (tid < 64) {
    unsigned v = (tid < 32) ? ((const unsigned*)mref)[p * 32 + tid]
                            : ((const unsigned*)msrc)[p * 32 + (tid - 32)];
    unsigned long long any = __ballot(v > 1u);
    if (tid == 0) masku8_s = any ? 1u : 0u;
  }
  // stage the 128x128 tile: 16 independent coalesced float4 loads
  {
    const float4* S4 = (const float4*)(scores + (size_t)p * NN2);
    float4 vv[16];
#pragma unroll
    for (int s = 0; s < 16; ++s)
      vv[s] = S4[s * 256 + tid];
#pragma unroll
    for (int s = 0; s < 16; ++s) {
      int flat = (s * 256 + tid) * 4;
      int r = flat >> 7, c = flat & 127;
      *(float4*)&tile[r * 132 + c] = vv[s];
    }
  }
  __syncthreads();
  const unsigned maskU8 = masku8_s;
  if (tid < NPT)
    lmr[tid] = maskU8 ? (((const unsigned char*)mref)[p * NPT + tid] != 0)
                      : (((const int*)mref)[p * NPT + tid] != 0);
  const int col = tid & 127;
  const int half = tid >> 7;
  const bool msj = maskU8 ? (((const unsigned char*)msrc)[p * NPT + col] != 0)
                          : (((const int*)msrc)[p * NPT + col] != 0);
  // row top-3: 8 lanes/row, b128 reads, shuffle-xor merge
  for (int rb = 0; rb < 4; ++rb) {
    int r = rb * 32 + (tid >> 3);
    int o = tid & 7;
    float a = NEGF, b = NEGF, c = NEGF;
    const float4* tr = (const float4*)&tile[r * 132 + o * 16];
#pragma unroll
    for (int k = 0; k < 4; ++k) {
      float4 q = tr[k];
      top3_upd(q.x, a, b, c); top3_upd(q.y, a, b, c);
      top3_upd(q.z, a, b, c); top3_upd(q.w, a, b, c);
    }
#pragma unroll
    for (int m = 1; m < 8; m <<= 1) {
      float pa = __shfl_xor(a, m, 64), pb = __shfl_xor(b, m, 64), pc = __shfl_xor(c, m, 64);
      merge3(a, b, c, pa, pb, pc);
    }
    if (o == 0) rthr[r] = c;
  }
  // col top-3: consecutive-lane conflict-free LDS reads
  {
    float a = NEGF, b = NEGF, c = NEGF;
    const float* tc = tile + (half * 64) * 132 + col;
#pragma unroll 8
    for (int r = 0; r < 64; ++r)
      top3_upd(tc[r * 132], a, b, c);
    colpart[half][col][0] = a; colpart[half][col][1] = b; colpart[half][col][2] = c;
  }
  __syncthreads();
  if (tid < NPT) {
    float a = colpart[0][tid][0], b = colpart[0][tid][1], c = colpart[0][tid][2];
    merge3(a, b, c, colpart[1][tid][0], colpart[1][tid][1], colpart[1][tid][2]);
    cthr[tid] = c;
  }
  __syncthreads();
  // corr scan: append to this proposal's private global list (no global atomics)
  {
    const float cth = cthr[col];
    const float* tc = tile + (half * 64) * 132 + col;
#pragma unroll 4
    for (int it = 0; it < 64; ++it) {
      float v = tc[it * 132];
      int i = half * 64 + it;
      if (msj && v >= cth && v >= rthr[i] && lmr[i] && (expf(v) > THRESH)) {
        unsigned pos = atomicAdd(&lcnt, 1u);   // LDS atomic only
        if (pos < MAXCPB) {
          unsigned long long key =
              (((unsigned long long)(~enc_f(v))) << 32) |
              (unsigned long long)(unsigned)(p * NN2 + i * NPT + col);
          clist[(size_t)p * MAXCPB + pos] = key;
        }
      }
    }
  }
  __syncthreads();
  if (tid == 0) ccnt[p] = (lcnt < MAXCPB) ? lcnt : MAXCPB;
}

// ---------------- partial histograms: 64 blocks x 16 proposals, no atomics out ----
__global__ __launch_bounds__(256) void k_hist(
    const unsigned* __restrict__ ccnt, const unsigned long long* __restrict__ clist,
    unsigned* __restrict__ phist) {
  __shared__ unsigned lh[4096];
  const int b = blockIdx.x, tid = threadIdx.x;
  for (int i = tid; i < 4096; i += 256) lh[i] = 0;
  __syncthreads();
  for (int q = 0; q < 16; ++q) {
    const int p = b * 16 + q;
    const unsigned cnt = min(ccnt[p], (unsigned)MAXCPB);
    const unsigned long long* my = clist + (size_t)p * MAXCPB;
    for (unsigned t = tid; t < cnt; t += 256)
      atomicAdd(&lh[(unsigned)(my[t] >> 52)], 1u);
  }
  __syncthreads();
  for (int i = tid; i < 4096; i += 256) phist[b * 4096 + i] = lh[i];
}

// ---------------- reduce partials, find cutoff bin ----------------
__global__ __launch_bounds__(1024) void k_cut(const unsigned* __restrict__ phist,
                                              unsigned* __restrict__ hdr) {
  __shared__ unsigned s[1024];
  __shared__ unsigned cb_s;
  const int tid = threadIdx.x;
  if (tid == 0) cb_s = 4095u;
  uint4 acc = make_uint4(0, 0, 0, 0);
  const uint4* ph4 = (const uint4*)phist;
#pragma unroll 4
  for (int b = 0; b < 64; ++b) {
    uint4 h = ph4[b * 1024 + tid];
    acc.x += h.x; acc.y += h.y; acc.z += h.z; acc.w += h.w;
  }
  s[tid] = acc.x + acc.y + acc.z + acc.w;
  __syncthreads();
  for (int off = 1; off < 1024; off <<= 1) {
    unsigned v = s[tid];
    unsigned a = (tid >= off) ? s[tid - off] : 0u;
    __syncthreads();
    s[tid] = v + a;
    __syncthreads();
  }
  {
    unsigned pre = (tid > 0) ? s[tid - 1] : 0u;
    unsigned tot4 = acc.x + acc.y + acc.z + acc.w;
    if (pre < MAXC && pre + tot4 >= MAXC) {   // unique thread
      unsigned c0 = pre + acc.x, c1 = c0 + acc.y, c2 = c1 + acc.z;
      cb_s = (c0 >= MAXC) ? tid * 4 : (c1 >= MAXC) ? tid * 4 + 1
           : (c2 >= MAXC) ? tid * 4 + 2 : tid * 4 + 3;
    }
  }
  __syncthreads();
  if (tid == 0) {
    hdr[0] = s[1023];   // total corr count
    hdr[1] = 0u;        // sel counter (for k_gather)
    hdr[2] = cb_s;      // cutoff bin
  }
}

// ---------------- gather survivors (wave-aggregated appends) ----------------
__global__ __launch_bounds__(256) void k_gather(
    const unsigned* __restrict__ ccnt, const unsigned long long* __restrict__ clist,
    unsigned* __restrict__ hdr, unsigned long long* __restrict__ sel) {
  const int b = blockIdx.x, tid = threadIdx.x, lane = tid & 63;
  const unsigned cut = hdr[2];
  for (int q = 0; q < 16; ++q) {
    const int p = b * 16 + q;
    const unsigned cnt = min(ccnt[p], (unsigned)MAXCPB);
    const unsigned long long* my = clist + (size_t)p * MAXCPB;
    for (unsigned t0 = 0; t0 < cnt; t0 += 256) {
      unsigned t = t0 + tid;
      unsigned long long key = 0;
      bool take = false;
      if (t < cnt) {
        key = my[t];
        take = ((unsigned)(key >> 52)) <= cut;
      }
      unsigned long long mb = __ballot(take);
      if (mb) {
        int leader = __ffsll((unsigned long long)mb) - 1;
        unsigned base = 0;
        if (lane == leader) base = atomicAdd(&hdr[1], (unsigned)__popcll(mb));
        base = __shfl(base, leader, 64);
        if (take) {
          unsigned pos = base + (unsigned)__popcll(mb & ((1ull << lane) - 1ull));
          if (pos < SELCAP) sel[pos] = key;
        }
      }
    }
  }
}

// ---- sort (wave-synchronous LDS bitonic, pair-indexed) + write outputs/pool ----
__global__ __launch_bounds__(1024) void k_sortout(
    const unsigned long long* __restrict__ sel, const unsigned* __restrict__ hdr,
    const float* __restrict__ refp, const float* __restrict__ srcp,
    float* __restrict__ pool, float* __restrict__ out) {
  __shared__ unsigned long long keys[4096];
  const int tid = threadIdx.x;
  const unsigned sc = min(hdr[1], SELCAP);
  const unsigned n2 = (sc <= 2048u) ? 2048u : 4096u;
  for (unsigned t = tid; t < n2; t += 1024)
    keys[t] = (t < sc) ? sel[t] : 0xFFFFFFFFFFFFFFFFull;
  __syncthreads();
  const unsigned chunk = n2 >> 4;          // 16 waves, one aligned chunk each
  const unsigned w = tid >> 6, lane = tid & 63;
  const unsigned base = w * chunk;
  for (unsigned k = 2; k <= n2; k <<= 1) {
    unsigned j = k >> 1;
    // block-wide passes while pairs cross chunk boundaries
    for (; j >= chunk; j >>= 1) {
      for (unsigned q = tid; q < (n2 >> 1); q += 1024) {
        unsigned t = ((q & ~(j - 1u)) << 1) | (q & (j - 1u));
        unsigned u = t | j;
        bool up = ((t & k) == 0u);
        unsigned long long A = keys[t], B = keys[u];
        if (up ? (A > B) : (A < B)) { keys[t] = B; keys[u] = A; }
      }
      __syncthreads();
    }
    // wave-local passes: j < chunk, each wave owns its aligned chunk
    for (; j; j >>= 1) {
      for (unsigned q = lane; q < (chunk >> 1); q += 64) {
        unsigned lt = ((q & ~(j - 1u)) << 1) | (q & (j - 1u));
        unsigned t = base + lt;
        unsigned u = t | j;                // stays inside the chunk
        bool up = ((t & k) == 0u);
        unsigned long long A = keys[t], B = keys[u];
        if (up ? (A > B) : (A < B)) { keys[t] = B; keys[u] = A; }
      }
      // no barrier: same-wave LDS ops execute in order; pairs are disjoint
    }
    __syncthreads();
  }
  const unsigned stotal = hdr[0];
  const unsigned nreal = (stotal < MAXC) ? stotal : MAXC;
  for (int mm = tid; mm < MAXC; mm += 1024) {
    unsigned flat; float score; bool real = ((unsigned)mm < nreal);
    if (real) {
      unsigned long long key = keys[mm];
      flat = (unsigned)(key & 0xFFFFFFFFull);
      score = expf(dec_f(~(unsigned)(key >> 32)));
    } else {
      flat = (unsigned)mm;
      score = 0.f;
    }
    unsigned p = flat >> 14, rem = flat & 16383u, i = rem >> 7, j = rem & 127u;
    float rx = refp[((size_t)p * NPT + i) * 3 + 0];
    float ry = refp[((size_t)p * NPT + i) * 3 + 1];
    float rz = refp[((size_t)p * NPT + i) * 3 + 2];
    float sx = srcp[((size_t)p * NPT + j) * 3 + 0];
    float sy = srcp[((size_t)p * NPT + j) * 3 + 1];
    float sz = srcp[((size_t)p * NPT + j) * 3 + 2];
    out[mm * 3 + 0] = rx; out[mm * 3 + 1] = ry; out[mm * 3 + 2] = rz;
    out[4500 + mm * 3 + 0] = sx; out[4500 + mm * 3 + 1] = sy; out[4500 + mm * 3 + 2] = sz;
    out[9000 + mm] = score;
    pool[mm * 3 + 0] = rx; pool[mm * 3 + 1] = ry; pool[mm * 3 + 2] = rz;
    pool[4500 + mm * 3 + 0] = sx; pool[4500 + mm * 3 + 1] = sy; pool[4500 + mm * 3 + 2] = sz;
    float pad = real ? 0.f : 1e6f;
    pool[9000 + mm * 3 + 0] = sx + pad;
    pool[9000 + mm * 3 + 1] = sy + pad;
    pool[9000 + mm * 3 + 2] = sz + pad;
    pool[13500 + mm] = score;
  }
}

// ---------------- per-proposal: stats from clist + Kabsch + inlier count ----------
__global__ __launch_bounds__(256) void k_evalT(
    const unsigned* __restrict__ ccnt, const unsigned long long* __restrict__ clist,
    const float* __restrict__ refp, const float* __restrict__ srcp,
    const float* __restrict__ pool, double* __restrict__ trans,
    int* __restrict__ icount) {
  const int p = blockIdx.x, tid = threadIdx.x, lane = tid & 63;
  __shared__ double red[4][16];
  __shared__ double Ts[12];
  __shared__ int redc[4];
  const unsigned cnt = min(ccnt[p], (unsigned)MAXCPB);
  double tot = 0, sr0 = 0, sr1 = 0, sr2 = 0, ss0 = 0, ss1 = 0, ss2 = 0;
  double m00 = 0, m01 = 0, m02 = 0, m10 = 0, m11 = 0, m12 = 0, m20 = 0, m21 = 0, m22 = 0;
  for (unsigned t = tid; t < cnt; t += 256) {
    unsigned long long key = clist[(size_t)p * MAXCPB + t];
    unsigned flat = (unsigned)(key & 0xFFFFFFFFull);
    unsigned rem = flat & 16383u, i = rem >> 7, j = rem & 127u;
    double w = (double)expf(dec_f(~(unsigned)(key >> 32)));
    double rx = refp[((size_t)p * NPT + i) * 3 + 0];
    double ry = refp[((size_t)p * NPT + i) * 3 + 1];
    double rz = refp[((size_t)p * NPT + i) * 3 + 2];
    double sx = srcp[((size_t)p * NPT + j) * 3 + 0];
    double sy = srcp[((size_t)p * NPT + j) * 3 + 1];
    double sz = srcp[((size_t)p * NPT + j) * 3 + 2];
    tot += w;
    sr0 += w * rx; sr1 += w * ry; sr2 += w * rz;
    ss0 += w * sx; ss1 += w * sy; ss2 += w * sz;
    double wsx = w * sx, wsy = w * sy, wsz = w * sz;
    m00 += wsx * rx; m01 += wsx * ry; m02 += wsx * rz;
    m10 += wsy * rx; m11 += wsy * ry; m12 += wsy * rz;
    m20 += wsz * rx; m21 += wsz * ry; m22 += wsz * rz;
  }
  double vals[16] = {tot, sr0, sr1, sr2, ss0, ss1, ss2,
                     m00, m01, m02, m10, m11, m12, m20, m21, m22};
#pragma unroll
  for (int k = 0; k < 16; ++k) {
    double x = vals[k];
    for (int o = 32; o; o >>= 1) x += __shfl_down(x, o, 64);
    if (lane == 0) red[tid >> 6][k] = x;
  }
  __syncthreads();
  if (tid == 0) {
    double s16[16];
#pragma unroll
    for (int k = 0; k < 16; ++k)
      s16[k] = red[0][k] + red[1][k] + red[2][k] + red[3][k];
    kabsch_from_sums(s16[0], s16 + 1, s16 + 4, s16 + 7, Ts);
    for (int k = 0; k < 12; ++k) trans[p * 12 + k] = Ts[k];
  }
  __syncthreads();
  double R00 = Ts[0], R01 = Ts[1], R02 = Ts[2], R10 = Ts[3], R11 = Ts[4], R12 = Ts[5];
  double R20 = Ts[6], R21 = Ts[7], R22 = Ts[8], t0 = Ts[9], t1 = Ts[10], t2 = Ts[11];
  const float* pr = pool;
  const float* pe = pool + 9000;
  int c = 0;
  for (int mm = tid; mm < MAXC; mm += 256) {
    double ex = pe[mm * 3], ey = pe[mm * 3 + 1], ez = pe[mm * 3 + 2];
    double ax = R00 * ex + R01 * ey + R02 * ez + t0;
    double ay = R10 * ex + R11 * ey + R12 * ez + t1;
    double az = R20 * ex + R21 * ey + R22 * ez + t2;
    double dx = pr[mm * 3] - ax, dy = pr[mm * 3 + 1] - ay, dz = pr[mm * 3 + 2] - az;
    if (dx * dx + dy * dy + dz * dz < RRD) ++c;
  }
  for (int o = 32; o; o >>= 1) c += __shfl_down(c, o, 64);
  if (lane == 0) redc[tid >> 6] = c;
  __syncthreads();
  if (tid == 0) {
    int tc = redc[0] + redc[1] + redc[2] + redc[3];
    icount[p] = (cnt >= 3u) ? tc : -1;
  }
}

// -------- argmax + iterative refinement: ONE WAVE, no barriers, no LDS --------
__global__ __launch_bounds__(64, 1) void k_refine(const double* __restrict__ trans,
                                                  const int* __restrict__ icount,
                                                  const float* __restrict__ pool,
                                                  float* __restrict__ out) {
  const int lane = threadIdx.x;
  // argmax (first-max semantics: strict > keeps lowest index; merges compare idx)
  int bc = -2147483647, bi = 0;
  for (int idx = lane; idx < PP; idx += 64) {
    int c = icount[idx];
    if (c > bc) { bc = c; bi = idx; }
  }
  for (int o = 32; o; o >>= 1) {
    int c2 = __shfl_down(bc, o, 64);
    int i2 = __shfl_down(bi, o, 64);
    if (c2 > bc || (c2 == bc && i2 < bi)) { bc = c2; bi = i2; }
  }
  bi = __shfl(bi, 0, 64);
  double T[12];
#pragma unroll
  for (int k = 0; k < 12; ++k) T[k] = trans[bi * 12 + k];  // all lanes same loads
  const float* pr = pool;
  const float* ps = pool + 4500;
  const float* pe = pool + 9000;
  const float* pw = pool + 13500;
  for (int iter = 0; iter < 5; ++iter) {
    double R00 = T[0], R01 = T[1], R02 = T[2], R10 = T[3], R11 = T[4], R12 = T[5];
    double R20 = T[6], R21 = T[7], R22 = T[8], t0 = T[9], t1 = T[10], t2 = T[11];
    double acc[16];
#pragma unroll
    for (int k = 0; k < 16; ++k) acc[k] = 0.0;
#pragma unroll 4
    for (int mm = lane; mm < MAXC; mm += 64) {
      double ex = pe[mm * 3], ey = pe[mm * 3 + 1], ez = pe[mm * 3 + 2];
      double ax = R00 * ex + R01 * ey + R02 * ez + t0;
      double ay = R10 * ex + R11 * ey + R12 * ez + t1;
      double az = R20 * ex + R21 * ey + R22 * ez + t2;
      double rx = pr[mm * 3], ry = pr[mm * 3 + 1], rz = pr[mm * 3 + 2];
      double dx = rx - ax, dy = ry - ay, dz = rz - az;
      if (dx * dx + dy * dy + dz * dz < RRD) {
        double w = (double)pw[mm];
        double sx = ps[mm * 3], sy = ps[mm * 3 + 1], sz = ps[mm * 3 + 2];
        acc[0] += w;
        acc[1] += w * rx; acc[2] += w * ry; acc[3] += w * rz;
        acc[4] += w * sx; acc[5] += w * sy; acc[6] += w * sz;
        double wsx = w * sx, wsy = w * sy, wsz = w * sz;
        acc[7]  += wsx * rx; acc[8]  += wsx * ry; acc[9]  += wsx * rz;
        acc[10] += wsy * rx; acc[11] += wsy * ry; acc[12] += wsy * rz;
        acc[13] += wsz * rx; acc[14] += wsz * ry; acc[15] += wsz * rz;
      }
    }
#pragma unroll
    for (int k = 0; k < 16; ++k)
      for (int o = 32; o; o >>= 1) acc[k] += __shfl_down(acc[k], o, 64);
    if (lane == 0)
      kabsch_from_sums(acc[0], acc + 1, acc + 4, acc + 7, T);
#pragma unroll
    for (int k = 0; k < 12; ++k) T[k] = __shfl(T[k], 0, 64);  // wave broadcast
  }
  if (lane == 0) {
    out[10500 + 0]  = (float)T[0]; out[10500 + 1]  = (float)T[1];
    out[10500 + 2]  = (float)T[2]; out[10500 + 3]  = (float)T[9];
    out[10500 + 4]  = (float)T[3]; out[10500 + 5]  = (float)T[4];
    out[10500 + 6]  = (float)T[5]; out[10500 + 7]  = (float)T[10];
    out[10500 + 8]  = (float)T[6]; out[10500 + 9]  = (float)T[7];
    out[10500 + 10] = (float)T[8]; out[10500 + 11] = (float)T[11];
    out[10500 + 12] = 0.f; out[10500 + 13] = 0.f;
    out[10500 + 14] = 0.f; out[10500 + 15] = 1.f;
  }
}

extern "C" void kernel_launch(void* const* d_in, const int* in_sizes, int n_in,
                              void* d_out, int out_size, void* d_ws, size_t ws_size,
                              hipStream_t stream) {
  const float* refp = (const float*)d_in[0];
  const float* srcp = (const float*)d_in[1];
  const void* mref = d_in[2];
  const void* msrc = d_in[3];
  const float* scores = (const float*)d_in[4];
  float* out = (float*)d_out;
  char* ws = (char*)d_ws;
  unsigned* ccnt = (unsigned*)(ws + OFF_CCNT);
  int* icount = (int*)(ws + OFF_ICNT);
  double* trans = (double*)(ws + OFF_TRANS);
  float* pool = (float*)(ws + OFF_POOL);
  unsigned* hdr = (unsigned*)(ws + OFF_HDR);
  unsigned long long* sel = (unsigned long long*)(ws + OFF_SEL);
  unsigned* phist = (unsigned*)(ws + OFF_PHIST);
  unsigned long long* clist = (unsigned long long*)(ws + OFF_CLIST);

  k_fused<<<PP, 256, 0, stream>>>(scores, mref, msrc, ccnt, clist);
  k_hist<<<64, 256, 0, stream>>>(ccnt, clist, phist);
  k_cut<<<1, 1024, 0, stream>>>(phist, hdr);
  k_gather<<<64, 256, 0, stream>>>(ccnt, clist, hdr, sel);
  k_sortout<<<1, 1024, 0, stream>>>(sel, hdr, refp, srcp, pool, out);
  k_evalT<<<PP, 256, 0, stream>>>(ccnt, clist, refp, srcp, pool, trans, icount);
  k_refine<<<1, 64, 0, stream>>>(trans, icount, pool, out);
}

// Round 11
// 295.306 us; speedup vs baseline: 1.0883x; 1.0868x over previous
//
#include <hip/hip_runtime.h>
#include <math.h>

#define PP    1024
#define NPT   128
#define NN2   16384
#define THRESH 0.05f
#define MAXC  1500
#define EPSD  1e-5
#define RRD   (0.1*0.1)
#define NEGF  -3.0e38f
#define MAXCPB 384      // mutual-top3 per proposal is mathematically <= 3*128
#define SELCAP 4096u

// ---- workspace byte offsets (everything written before read; no memsets) ----
#define OFF_CCNT  0          // u32[1024]                  -> 4096
#define OFF_ICNT  4096       // int[1024]                  -> 8192
#define OFF_TRANS 8192       // double[1024*12]            -> 106496
#define OFF_POOL  106496     // float[15000]               -> 166496
#define OFF_HDR   166496     // u32[16]: 0=total 1=selCnt 2=cutbin -> 166560
#define OFF_SEL   166560     // u64[4096]                  -> 199328
#define OFF_PHIST 199328     // u32[64*4096]               -> 1247904
#define OFF_CLIST 1247904    // u64[1024*384]              -> 4393632

// ---------------- branchless top-3 helpers ----------------
__device__ inline void top3_upd(float v, float& a, float& b, float& c) {
  float m1 = fminf(a, v);
  a = fmaxf(a, v);
  float m2 = fminf(b, m1);
  b = fmaxf(b, m1);
  c = fmaxf(c, m2);
}
__device__ inline void merge3(float& a, float& b, float& c, float x0, float x1, float x2) {
  float z0 = fmaxf(a, x0);
  float z1 = fmaxf(fminf(a, x0), fmaxf(b, x1));
  float z2 = fmaxf(fmaxf(c, x2), fmaxf(fminf(b, x0), fminf(a, x1)));
  a = z0; b = z1; c = z2;
}

// sortable float encoding (enc ascending == v ascending)
__device__ inline unsigned enc_f(float v) {
  unsigned b = __float_as_uint(v);
  return (b & 0x80000000u) ? ~b : (b | 0x80000000u);
}
__device__ inline float dec_f(unsigned enc) {
  unsigned b = (enc & 0x80000000u) ? (enc ^ 0x80000000u) : ~enc;
  return __uint_as_float(b);
}

// ---------------- Jacobi fallback (rare: near-degenerate eigenvalue gap) --------
__device__ void jacobi4(double A[4][4], double V[4][4]) {
  for (int i = 0; i < 4; ++i)
    for (int j = 0; j < 4; ++j) V[i][j] = (i == j) ? 1.0 : 0.0;
  const int PI_[6] = {0, 0, 0, 1, 1, 2};
  const int QI_[6] = {1, 2, 3, 2, 3, 3};
  for (int sweep = 0; sweep < 30; ++sweep) {
    double off = fabs(A[0][1]) + fabs(A[0][2]) + fabs(A[0][3]) +
                 fabs(A[1][2]) + fabs(A[1][3]) + fabs(A[2][3]);
    double dia = fabs(A[0][0]) + fabs(A[1][1]) + fabs(A[2][2]) + fabs(A[3][3]);
    if (off <= 1e-14 * (dia + 1e-300)) break;
    for (int r = 0; r < 6; ++r) {
      int p = PI_[r], q = QI_[r];
      double apq = A[p][q];
      if (fabs(apq) <= 1e-18 * (fabs(A[p][p]) + fabs(A[q][q]) + 1e-300)) continue;
      double theta = (A[q][q] - A[p][p]) / (2.0 * apq);
      double t = ((theta >= 0.0) ? 1.0 : -1.0) / (fabs(theta) + sqrt(1.0 + theta * theta));
      double c = 1.0 / sqrt(1.0 + t * t);
      double s = t * c;
      for (int k = 0; k < 4; ++k) {
        double akp = A[k][p], akq = A[k][q];
        A[k][p] = c * akp - s * akq;
        A[k][q] = s * akp + c * akq;
      }
      for (int k = 0; k < 4; ++k) {
        double apk = A[p][k], aqk = A[q][k];
        A[p][k] = c * apk - s * aqk;
        A[q][k] = s * apk + c * aqk;
      }
      for (int k = 0; k < 4; ++k) {
        double vkp = V[k][p], vkq = V[k][q];
        V[k][p] = c * vkp - s * vkq;
        V[k][q] = s * vkp + c * vkq;
      }
    }
  }
}

// sums are UN-normalized: tot=Σw, sr=Σw*ref, ss=Σw*src, m9[c*3+d]=Σw*src_c*ref_d
// Fully scalarized QCP (Theobald) with Jacobi fallback.
__device__ inline void kabsch_from_sums(double tot, const double* sr, const double* ss,
                                        const double* m9, double* T12) {
  double den = tot + EPSD;
  double rcx = sr[0] / den, rcy = sr[1] / den, rcz = sr[2] / den;
  double scx = ss[0] / den, scy = ss[1] / den, scz = ss[2] / den;
  double f = 2.0 - tot / den;
  double Sxx = m9[0] / den - f * scx * rcx;
  double Sxy = m9[1] / den - f * scx * rcy;
  double Sxz = m9[2] / den - f * scx * rcz;
  double Syx = m9[3] / den - f * scy * rcx;
  double Syy = m9[4] / den - f * scy * rcy;
  double Syz = m9[5] / den - f * scy * rcz;
  double Szx = m9[6] / den - f * scz * rcx;
  double Szy = m9[7] / den - f * scz * rcy;
  double Szz = m9[8] / den - f * scz * rcz;
  if (tot < EPSD) {
    Sxx = 3.0; Sxy = 0.0; Sxz = 0.0;
    Syx = 0.0; Syy = 2.0; Syz = 0.0;
    Szx = 0.0; Szy = 0.0; Szz = 1.0;
  }
  double n00 = Sxx + Syy + Szz, n01 = Syz - Szy, n02 = Szx - Sxz, n03 = Sxy - Syx;
  double n11 = Sxx - Syy - Szz, n12 = Sxy + Syx, n13 = Szx + Sxz;
  double n22 = -Sxx + Syy - Szz, n23 = Syz + Szy;
  double n33 = -Sxx - Syy + Szz;
  double fro2 = Sxx*Sxx + Sxy*Sxy + Sxz*Sxz + Syx*Syx + Syy*Syy + Syz*Syz +
                Szx*Szx + Szy*Szy + Szz*Szz;
  double c2 = -2.0 * fro2;
  double c1 = -8.0 * (Sxx * (Syy * Szz - Syz * Szy) -
                      Sxy * (Syx * Szz - Syz * Szx) +
                      Sxz * (Syx * Szy - Syy * Szx));
  double s0 = n00 * n11 - n01 * n01;
  double s1 = n00 * n12 - n02 * n01;
  double s2 = n00 * n13 - n03 * n01;
  double s3 = n01 * n12 - n02 * n11;
  double s4 = n01 * n13 - n03 * n11;
  double s5 = n02 * n13 - n03 * n12;
  double t0 = n02 * n13 - n12 * n03;
  double t1 = n02 * n23 - n22 * n03;
  double t2 = n02 * n33 - n23 * n03;
  double t3 = n12 * n23 - n22 * n13;
  double t4 = n12 * n33 - n23 * n13;
  double t5 = n22 * n33 - n23 * n23;
  double c0 = s0 * t5 - s1 * t4 + s2 * t3 + s3 * t2 - s4 * t1 + s5 * t0;
  double g0 = n00 + fabs(n01) + fabs(n02) + fabs(n03);
  double g1 = n11 + fabs(n01) + fabs(n12) + fabs(n13);
  double g2 = n22 + fabs(n02) + fabs(n12) + fabs(n23);
  double g3 = n33 + fabs(n03) + fabs(n13) + fabs(n23);
  double lam = fmax(fmax(g0, g1), fmax(g2, g3));
  for (int it = 0; it < 20; ++it) {
    double l2 = lam * lam;
    double pv = ((l2 + c2) * lam + c1) * lam + c0;
    double dp = (4.0 * l2 + 2.0 * c2) * lam + c1;
    if (dp == 0.0) break;
    double d = pv / dp;
    lam -= d;
    if (fabs(d) <= 1e-14 * fmax(fabs(lam), 1e-30)) break;
  }
  double e0 = n00 - lam, e1 = n01,       e2 = n02,       e3 = n03;
  double e4 = n01,       e5 = n11 - lam, e6 = n12,       e7 = n13;
  double e8 = n02,       e9 = n12,       e10 = n22 - lam, e11 = n23;
  double e12 = n03,      e13 = n13,      e14 = n23,      e15 = n33 - lam;
  double i0  =  e5*e10*e15 - e5*e11*e14 - e9*e6*e15 + e9*e7*e14 + e13*e6*e11 - e13*e7*e10;
  double i4  = -e4*e10*e15 + e4*e11*e14 + e8*e6*e15 - e8*e7*e14 - e12*e6*e11 + e12*e7*e10;
  double i8  =  e4*e9*e15  - e4*e11*e13 - e8*e5*e15 + e8*e7*e13 + e12*e5*e11 - e12*e7*e9;
  double i12 = -e4*e9*e14  + e4*e10*e13 + e8*e5*e14 - e8*e6*e13 - e12*e5*e10 + e12*e6*e9;
  double i1  = -e1*e10*e15 + e1*e11*e14 + e9*e2*e15 - e9*e3*e14 - e13*e2*e11 + e13*e3*e10;
  double i5  =  e0*e10*e15 - e0*e11*e14 - e8*e2*e15 + e8*e3*e14 + e12*e2*e11 - e12*e3*e10;
  double i9  = -e0*e9*e15  + e0*e11*e13 + e8*e1*e15 - e8*e3*e13 - e12*e1*e11 + e12*e3*e9;
  double i13 =  e0*e9*e14  - e0*e10*e13 - e8*e1*e14 + e8*e2*e13 + e12*e1*e10 - e12*e2*e9;
  double i2  =  e1*e6*e15  - e1*e7*e14  - e5*e2*e15 + e5*e3*e14 + e13*e2*e7  - e13*e3*e6;
  double i6  = -e0*e6*e15  + e0*e7*e14  + e4*e2*e15 - e4*e3*e14 - e12*e2*e7  + e12*e3*e6;
  double i10 =  e0*e5*e15  - e0*e7*e13  - e4*e1*e15 + e4*e3*e13 + e12*e1*e7  - e12*e3*e5;
  double i14 = -e0*e5*e14  + e0*e6*e13  + e4*e1*e14 - e4*e2*e13 - e12*e1*e6  + e12*e2*e5;
  double i3  = -e1*e6*e11  + e1*e7*e10  + e5*e2*e11 - e5*e3*e10 - e9*e2*e7   + e9*e3*e6;
  double i7  =  e0*e6*e11  - e0*e7*e10  - e4*e2*e11 + e4*e3*e10 + e8*e2*e7   - e8*e3*e6;
  double i11 = -e0*e5*e11  + e0*e7*e9   + e4*e1*e11 - e4*e3*e9  - e8*e1*e7   + e8*e3*e5;
  double i15 =  e0*e5*e10  - e0*e6*e9   - e4*e1*e10 + e4*e2*e9  + e8*e1*e6   - e8*e2*e5;
  double d0 = fabs(i0), d1 = fabs(i5), d2 = fabs(i10), d3 = fabs(i15);
  double v0, v1, v2, v3;
  if (d0 >= d1 && d0 >= d2 && d0 >= d3)      { v0 = i0;  v1 = i1;  v2 = i2;  v3 = i3;  }
  else if (d1 >= d2 && d1 >= d3)             { v0 = i4;  v1 = i5;  v2 = i6;  v3 = i7;  }
  else if (d2 >= d3)                         { v0 = i8;  v1 = i9;  v2 = i10; v3 = i11; }
  else                                       { v0 = i12; v1 = i13; v2 = i14; v3 = i15; }
  double vn2 = v0 * v0 + v1 * v1 + v2 * v2 + v3 * v3;
  double scl = sqrt(fro2) + fabs(lam) + 1e-300;
  double thr = 1e-10 * scl * scl * scl;
  double q0, qx, qy, qz;
  if (vn2 > thr * thr) {
    double inv = 1.0 / sqrt(vn2);
    q0 = v0 * inv; qx = v1 * inv; qy = v2 * inv; qz = v3 * inv;
  } else {
    double A[4][4] = {{n00, n01, n02, n03}, {n01, n11, n12, n13},
                      {n02, n12, n22, n23}, {n03, n13, n23, n33}};
    double V[4][4];
    jacobi4(A, V);
    int kb = 0; double ev = A[0][0];
    for (int i = 1; i < 4; ++i) if (A[i][i] > ev) { ev = A[i][i]; kb = i; }
    double w0 = V[0][kb], w1 = V[1][kb], w2 = V[2][kb], w3 = V[3][kb];
    double nr = sqrt(w0 * w0 + w1 * w1 + w2 * w2 + w3 * w3);
    if (nr < 1e-300) { w0 = 1.0; w1 = w2 = w3 = 0.0; nr = 1.0; }
    q0 = w0 / nr; qx = w1 / nr; qy = w2 / nr; qz = w3 / nr;
  }
  double R00 = q0*q0 + qx*qx - qy*qy - qz*qz, R01 = 2.0*(qx*qy - q0*qz), R02 = 2.0*(qx*qz + q0*qy);
  double R10 = 2.0*(qx*qy + q0*qz), R11 = q0*q0 - qx*qx + qy*qy - qz*qz, R12 = 2.0*(qy*qz - q0*qx);
  double R20 = 2.0*(qx*qz - q0*qy), R21 = 2.0*(qy*qz + q0*qx), R22 = q0*q0 - qx*qx - qy*qy + qz*qz;
  T12[0] = R00; T12[1] = R01; T12[2] = R02;
  T12[3] = R10; T12[4] = R11; T12[5] = R12;
  T12[6] = R20; T12[7] = R21; T12[8] = R22;
  T12[9]  = rcx - (R00 * scx + R01 * scy + R02 * scz);
  T12[10] = rcy - (R10 * scx + R11 * scy + R12 * scz);
  T12[11] = rcz - (R20 * scx + R21 * scy + R22 * scz);
}

// ---------------- fused: stage tile, thresholds, scan -> per-proposal corr list ----
__global__ __launch_bounds__(256, 2) void k_fused(
    const float* __restrict__ scores, const void* __restrict__ mref,
    const void* __restrict__ msrc, unsigned* __restrict__ ccnt,
    unsigned long long* __restrict__ clist) {
  const int p = blockIdx.x;
  const int tid = threadIdx.x;
  __shared__ float tile[128 * 132];
  __shared__ float colpart[2][NPT][3];
  __shared__ float rthr[NPT], cthr[NPT];
  __shared__ unsigned char lmr[NPT];
  __shared__ unsigned lcnt;
  __shared__ unsigned masku8_s;
  if (tid == 0) lcnt = 0;
  if (tid < 64) {
    unsigned v = (tid < 32) ? ((const unsigned*)mref)[p * 32 + tid]
                            : ((const unsigned*)msrc)[p * 32 + (tid - 32)];
    unsigned long long any = __ballot(v > 1u);
    if (tid == 0) masku8_s = any ? 1u : 0u;
  }
  {
    const float4* S4 = (const float4*)(scores + (size_t)p * NN2);
    float4 vv[16];
#pragma unroll
    for (int s = 0; s < 16; ++s)
      vv[s] = S4[s * 256 + tid];
#pragma unroll
    for (int s = 0; s < 16; ++s) {
      int flat = (s * 256 + tid) * 4;
      int r = flat >> 7, c = flat & 127;
      *(float4*)&tile[r * 132 + c] = vv[s];
    }
  }
  __syncthreads();
  const unsigned maskU8 = masku8_s;
  if (tid < NPT)
    lmr[tid] = maskU8 ? (((const unsigned char*)mref)[p * NPT + tid] != 0)
                      : (((const int*)mref)[p * NPT + tid] != 0);
  const int col = tid & 127;
  const int half = tid >> 7;
  const bool msj = maskU8 ? (((const unsigned char*)msrc)[p * NPT + col] != 0)
                          : (((const int*)msrc)[p * NPT + col] != 0);
  for (int rb = 0; rb < 4; ++rb) {
    int r = rb * 32 + (tid >> 3);
    int o = tid & 7;
    float a = NEGF, b = NEGF, c = NEGF;
    const float4* tr = (const float4*)&tile[r * 132 + o * 16];
#pragma unroll
    for (int k = 0; k < 4; ++k) {
      float4 q = tr[k];
      top3_upd(q.x, a, b, c); top3_upd(q.y, a, b, c);
      top3_upd(q.z, a, b, c); top3_upd(q.w, a, b, c);
    }
#pragma unroll
    for (int m = 1; m < 8; m <<= 1) {
      float pa = __shfl_xor(a, m, 64), pb = __shfl_xor(b, m, 64), pc = __shfl_xor(c, m, 64);
      merge3(a, b, c, pa, pb, pc);
    }
    if (o == 0) rthr[r] = c;
  }
  {
    float a = NEGF, b = NEGF, c = NEGF;
    const float* tc = tile + (half * 64) * 132 + col;
#pragma unroll 8
    for (int r = 0; r < 64; ++r)
      top3_upd(tc[r * 132], a, b, c);
    colpart[half][col][0] = a; colpart[half][col][1] = b; colpart[half][col][2] = c;
  }
  __syncthreads();
  if (tid < NPT) {
    float a = colpart[0][tid][0], b = colpart[0][tid][1], c = colpart[0][tid][2];
    merge3(a, b, c, colpart[1][tid][0], colpart[1][tid][1], colpart[1][tid][2]);
    cthr[tid] = c;
  }
  __syncthreads();
  {
    const float cth = cthr[col];
    const float* tc = tile + (half * 64) * 132 + col;
#pragma unroll 4
    for (int it = 0; it < 64; ++it) {
      float v = tc[it * 132];
      int i = half * 64 + it;
      if (msj && v >= cth && v >= rthr[i] && lmr[i] && (expf(v) > THRESH)) {
        unsigned pos = atomicAdd(&lcnt, 1u);   // LDS atomic only
        if (pos < MAXCPB) {
          unsigned long long key =
              (((unsigned long long)(~enc_f(v))) << 32) |
              (unsigned long long)(unsigned)(p * NN2 + i * NPT + col);
          clist[(size_t)p * MAXCPB + pos] = key;
        }
      }
    }
  }
  __syncthreads();
  if (tid == 0) ccnt[p] = (lcnt < MAXCPB) ? lcnt : MAXCPB;
}

// ---------------- partial histograms: 64 blocks x 16 proposals, no atomics out ----
__global__ __launch_bounds__(256) void k_hist(
    const unsigned* __restrict__ ccnt, const unsigned long long* __restrict__ clist,
    unsigned* __restrict__ phist) {
  __shared__ unsigned lh[4096];
  const int b = blockIdx.x, tid = threadIdx.x;
  for (int i = tid; i < 4096; i += 256) lh[i] = 0;
  __syncthreads();
  for (int q = 0; q < 16; ++q) {
    const int p = b * 16 + q;
    const unsigned cnt = min(ccnt[p], (unsigned)MAXCPB);
    const unsigned long long* my = clist + (size_t)p * MAXCPB;
    for (unsigned t = tid; t < cnt; t += 256)
      atomicAdd(&lh[(unsigned)(my[t] >> 52)], 1u);
  }
  __syncthreads();
  for (int i = tid; i < 4096; i += 256) phist[b * 4096 + i] = lh[i];
}

// ---------------- reduce partials, find cutoff bin ----------------
__global__ __launch_bounds__(1024) void k_cut(const unsigned* __restrict__ phist,
                                              unsigned* __restrict__ hdr) {
  __shared__ unsigned s[1024];
  __shared__ unsigned cb_s;
  const int tid = threadIdx.x;
  if (tid == 0) cb_s = 4095u;
  uint4 acc = make_uint4(0, 0, 0, 0);
  const uint4* ph4 = (const uint4*)phist;
#pragma unroll 4
  for (int b = 0; b < 64; ++b) {
    uint4 h = ph4[b * 1024 + tid];
    acc.x += h.x; acc.y += h.y; acc.z += h.z; acc.w += h.w;
  }
  s[tid] = acc.x + acc.y + acc.z + acc.w;
  __syncthreads();
  for (int off = 1; off < 1024; off <<= 1) {
    unsigned v = s[tid];
    unsigned a = (tid >= off) ? s[tid - off] : 0u;
    __syncthreads();
    s[tid] = v + a;
    __syncthreads();
  }
  {
    unsigned pre = (tid > 0) ? s[tid - 1] : 0u;
    unsigned tot4 = acc.x + acc.y + acc.z + acc.w;
    if (pre < MAXC && pre + tot4 >= MAXC) {   // unique thread
      unsigned c0 = pre + acc.x, c1 = c0 + acc.y, c2 = c1 + acc.z;
      cb_s = (c0 >= MAXC) ? tid * 4 : (c1 >= MAXC) ? tid * 4 + 1
           : (c2 >= MAXC) ? tid * 4 + 2 : tid * 4 + 3;
    }
  }
  __syncthreads();
  if (tid == 0) {
    hdr[0] = s[1023];   // total corr count
    hdr[1] = 0u;        // sel counter (for k_gather)
    hdr[2] = cb_s;      // cutoff bin
  }
}

// ---------------- gather survivors (wave-aggregated appends) ----------------
__global__ __launch_bounds__(256) void k_gather(
    const unsigned* __restrict__ ccnt, const unsigned long long* __restrict__ clist,
    unsigned* __restrict__ hdr, unsigned long long* __restrict__ sel) {
  const int b = blockIdx.x, tid = threadIdx.x, lane = tid & 63;
  const unsigned cut = hdr[2];
  for (int q = 0; q < 16; ++q) {
    const int p = b * 16 + q;
    const unsigned cnt = min(ccnt[p], (unsigned)MAXCPB);
    const unsigned long long* my = clist + (size_t)p * MAXCPB;
    for (unsigned t0 = 0; t0 < cnt; t0 += 256) {
      unsigned t = t0 + tid;
      unsigned long long key = 0;
      bool take = false;
      if (t < cnt) {
        key = my[t];
        take = ((unsigned)(key >> 52)) <= cut;
      }
      unsigned long long mb = __ballot(take);
      if (mb) {
        int leader = __ffsll((unsigned long long)mb) - 1;
        unsigned base = 0;
        if (lane == leader) base = atomicAdd(&hdr[1], (unsigned)__popcll(mb));
        base = __shfl(base, leader, 64);
        if (take) {
          unsigned pos = base + (unsigned)__popcll(mb & ((1ull << lane) - 1ull));
          if (pos < SELCAP) sel[pos] = key;
        }
      }
    }
  }
}

// ---- sort (wave-synchronous LDS bitonic, pair-indexed) + write outputs/pool ----
__global__ __launch_bounds__(1024) void k_sortout(
    const unsigned long long* __restrict__ sel, const unsigned* __restrict__ hdr,
    const float* __restrict__ refp, const float* __restrict__ srcp,
    float* __restrict__ pool, float* __restrict__ out) {
  __shared__ unsigned long long keys[4096];
  const int tid = threadIdx.x;
  const unsigned sc = min(hdr[1], SELCAP);
  const unsigned n2 = (sc <= 2048u) ? 2048u : 4096u;
  for (unsigned t = tid; t < n2; t += 1024)
    keys[t] = (t < sc) ? sel[t] : 0xFFFFFFFFFFFFFFFFull;
  __syncthreads();
  const unsigned chunk = n2 >> 4;          // 16 waves, one aligned chunk each
  const unsigned w = tid >> 6, lane = tid & 63;
  const unsigned base = w * chunk;
  for (unsigned k = 2; k <= n2; k <<= 1) {
    unsigned j = k >> 1;
    for (; j >= chunk; j >>= 1) {
      for (unsigned q = tid; q < (n2 >> 1); q += 1024) {
        unsigned t = ((q & ~(j - 1u)) << 1) | (q & (j - 1u));
        unsigned u = t | j;
        bool up = ((t & k) == 0u);
        unsigned long long A = keys[t], B = keys[u];
        if (up ? (A > B) : (A < B)) { keys[t] = B; keys[u] = A; }
      }
      __syncthreads();
    }
    for (; j; j >>= 1) {
      for (unsigned q = lane; q < (chunk >> 1); q += 64) {
        unsigned lt = ((q & ~(j - 1u)) << 1) | (q & (j - 1u));
        unsigned t = base + lt;
        unsigned u = t | j;
        bool up = ((t & k) == 0u);
        unsigned long long A = keys[t], B = keys[u];
        if (up ? (A > B) : (A < B)) { keys[t] = B; keys[u] = A; }
      }
    }
    __syncthreads();
  }
  const unsigned stotal = hdr[0];
  const unsigned nreal = (stotal < MAXC) ? stotal : MAXC;
  for (int mm = tid; mm < MAXC; mm += 1024) {
    unsigned flat; float score; bool real = ((unsigned)mm < nreal);
    if (real) {
      unsigned long long key = keys[mm];
      flat = (unsigned)(key & 0xFFFFFFFFull);
      score = expf(dec_f(~(unsigned)(key >> 32)));
    } else {
      flat = (unsigned)mm;
      score = 0.f;
    }
    unsigned p = flat >> 14, rem = flat & 16383u, i = rem >> 7, j = rem & 127u;
    float rx = refp[((size_t)p * NPT + i) * 3 + 0];
    float ry = refp[((size_t)p * NPT + i) * 3 + 1];
    float rz = refp[((size_t)p * NPT + i) * 3 + 2];
    float sx = srcp[((size_t)p * NPT + j) * 3 + 0];
    float sy = srcp[((size_t)p * NPT + j) * 3 + 1];
    float sz = srcp[((size_t)p * NPT + j) * 3 + 2];
    out[mm * 3 + 0] = rx; out[mm * 3 + 1] = ry; out[mm * 3 + 2] = rz;
    out[4500 + mm * 3 + 0] = sx; out[4500 + mm * 3 + 1] = sy; out[4500 + mm * 3 + 2] = sz;
    out[9000 + mm] = score;
    pool[mm * 3 + 0] = rx; pool[mm * 3 + 1] = ry; pool[mm * 3 + 2] = rz;
    pool[4500 + mm * 3 + 0] = sx; pool[4500 + mm * 3 + 1] = sy; pool[4500 + mm * 3 + 2] = sz;
    float pad = real ? 0.f : 1e6f;
    pool[9000 + mm * 3 + 0] = sx + pad;
    pool[9000 + mm * 3 + 1] = sy + pad;
    pool[9000 + mm * 3 + 2] = sz + pad;
    pool[13500 + mm] = score;
  }
}

// ---------------- per-proposal: stats from clist + Kabsch + inlier count ----------
__global__ __launch_bounds__(256) void k_evalT(
    const unsigned* __restrict__ ccnt, const unsigned long long* __restrict__ clist,
    const float* __restrict__ refp, const float* __restrict__ srcp,
    const float* __restrict__ pool, double* __restrict__ trans,
    int* __restrict__ icount) {
  const int p = blockIdx.x, tid = threadIdx.x, lane = tid & 63;
  __shared__ double red[4][16];
  __shared__ double Ts[12];
  __shared__ int redc[4];
  const unsigned cnt = min(ccnt[p], (unsigned)MAXCPB);
  double tot = 0, sr0 = 0, sr1 = 0, sr2 = 0, ss0 = 0, ss1 = 0, ss2 = 0;
  double m00 = 0, m01 = 0, m02 = 0, m10 = 0, m11 = 0, m12 = 0, m20 = 0, m21 = 0, m22 = 0;
  for (unsigned t = tid; t < cnt; t += 256) {
    unsigned long long key = clist[(size_t)p * MAXCPB + t];
    unsigned flat = (unsigned)(key & 0xFFFFFFFFull);
    unsigned rem = flat & 16383u, i = rem >> 7, j = rem & 127u;
    double w = (double)expf(dec_f(~(unsigned)(key >> 32)));
    double rx = refp[((size_t)p * NPT + i) * 3 + 0];
    double ry = refp[((size_t)p * NPT + i) * 3 + 1];
    double rz = refp[((size_t)p * NPT + i) * 3 + 2];
    double sx = srcp[((size_t)p * NPT + j) * 3 + 0];
    double sy = srcp[((size_t)p * NPT + j) * 3 + 1];
    double sz = srcp[((size_t)p * NPT + j) * 3 + 2];
    tot += w;
    sr0 += w * rx; sr1 += w * ry; sr2 += w * rz;
    ss0 += w * sx; ss1 += w * sy; ss2 += w * sz;
    double wsx = w * sx, wsy = w * sy, wsz = w * sz;
    m00 += wsx * rx; m01 += wsx * ry; m02 += wsx * rz;
    m10 += wsy * rx; m11 += wsy * ry; m12 += wsy * rz;
    m20 += wsz * rx; m21 += wsz * ry; m22 += wsz * rz;
  }
  double vals[16] = {tot, sr0, sr1, sr2, ss0, ss1, ss2,
                     m00, m01, m02, m10, m11, m12, m20, m21, m22};
#pragma unroll
  for (int k = 0; k < 16; ++k) {
    double x = vals[k];
    for (int o = 32; o; o >>= 1) x += __shfl_down(x, o, 64);
    if (lane == 0) red[tid >> 6][k] = x;
  }
  __syncthreads();
  if (tid == 0) {
    double s16[16];
#pragma unroll
    for (int k = 0; k < 16; ++k)
      s16[k] = red[0][k] + red[1][k] + red[2][k] + red[3][k];
    kabsch_from_sums(s16[0], s16 + 1, s16 + 4, s16 + 7, Ts);
    for (int k = 0; k < 12; ++k) trans[p * 12 + k] = Ts[k];
  }
  __syncthreads();
  double R00 = Ts[0], R01 = Ts[1], R02 = Ts[2], R10 = Ts[3], R11 = Ts[4], R12 = Ts[5];
  double R20 = Ts[6], R21 = Ts[7], R22 = Ts[8], t0 = Ts[9], t1 = Ts[10], t2 = Ts[11];
  const float* pr = pool;
  const float* pe = pool + 9000;
  int c = 0;
  for (int mm = tid; mm < MAXC; mm += 256) {
    double ex = pe[mm * 3], ey = pe[mm * 3 + 1], ez = pe[mm * 3 + 2];
    double ax = R00 * ex + R01 * ey + R02 * ez + t0;
    double ay = R10 * ex + R11 * ey + R12 * ez + t1;
    double az = R20 * ex + R21 * ey + R22 * ez + t2;
    double dx = pr[mm * 3] - ax, dy = pr[mm * 3 + 1] - ay, dz = pr[mm * 3 + 2] - az;
    if (dx * dx + dy * dy + dz * dz < RRD) ++c;
  }
  for (int o = 32; o; o >>= 1) c += __shfl_down(c, o, 64);
  if (lane == 0) redc[tid >> 6] = c;
  __syncthreads();
  if (tid == 0) {
    int tc = redc[0] + redc[1] + redc[2] + redc[3];
    icount[p] = (cnt >= 3u) ? tc : -1;
  }
}

// ---- argmax + iterative refinement: 512 threads (8 waves), branchless body ----
__global__ __launch_bounds__(512, 1) void k_refine(const double* __restrict__ trans,
                                                   const int* __restrict__ icount,
                                                   const float* __restrict__ pool,
                                                   float* __restrict__ out) {
  const int tid = threadIdx.x;
  const int lane = tid & 63;
  const int w = tid >> 6;
  __shared__ double red[8][16];
  __shared__ int rcs[8], ris[8];
  // argmax with first-max semantics (strict > keeps lowest index within a lane;
  // merges compare index)
  int bc = -2147483647, bi = 0;
  for (int idx = tid; idx < PP; idx += 512) {
    int c = icount[idx];
    if (c > bc) { bc = c; bi = idx; }
  }
  for (int o = 32; o; o >>= 1) {
    int c2 = __shfl_down(bc, o, 64);
    int i2 = __shfl_down(bi, o, 64);
    if (c2 > bc || (c2 == bc && i2 < bi)) { bc = c2; bi = i2; }
  }
  if (lane == 0) { rcs[w] = bc; ris[w] = bi; }
  __syncthreads();
  bc = rcs[0]; bi = ris[0];
#pragma unroll
  for (int q = 1; q < 8; ++q) {
    int c2 = rcs[q], i2 = ris[q];
    if (c2 > bc || (c2 == bc && i2 < bi)) { bc = c2; bi = i2; }
  }
  double T[12];
#pragma unroll
  for (int k = 0; k < 12; ++k) T[k] = trans[bi * 12 + k];  // same addr, all threads
  const float* pr = pool;
  const float* ps = pool + 4500;
  const float* pe = pool + 9000;
  const float* pw = pool + 13500;
  for (int iter = 0; iter < 5; ++iter) {
    double R00 = T[0], R01 = T[1], R02 = T[2], R10 = T[3], R11 = T[4], R12 = T[5];
    double R20 = T[6], R21 = T[7], R22 = T[8], t0 = T[9], t1 = T[10], t2 = T[11];
    double acc[16];
#pragma unroll
    for (int k = 0; k < 16; ++k) acc[k] = 0.0;
    for (int mm = tid; mm < MAXC; mm += 512) {
      // branchless: load everything, zero the weight for outliers (+0.0 == no-op)
      double ex = pe[mm * 3], ey = pe[mm * 3 + 1], ez = pe[mm * 3 + 2];
      double rx = pr[mm * 3], ry = pr[mm * 3 + 1], rz = pr[mm * 3 + 2];
      double sx = ps[mm * 3], sy = ps[mm * 3 + 1], sz = ps[mm * 3 + 2];
      double wv = (double)pw[mm];
      double ax = R00 * ex + R01 * ey + R02 * ez + t0;
      double ay = R10 * ex + R11 * ey + R12 * ez + t1;
      double az = R20 * ex + R21 * ey + R22 * ez + t2;
      double dx = rx - ax, dy = ry - ay, dz = rz - az;
      double w2 = (dx * dx + dy * dy + dz * dz < RRD) ? wv : 0.0;
      acc[0] += w2;
      acc[1] += w2 * rx; acc[2] += w2 * ry; acc[3] += w2 * rz;
      acc[4] += w2 * sx; acc[5] += w2 * sy; acc[6] += w2 * sz;
      double wsx = w2 * sx, wsy = w2 * sy, wsz = w2 * sz;
      acc[7]  += wsx * rx; acc[8]  += wsx * ry; acc[9]  += wsx * rz;
      acc[10] += wsy * rx; acc[11] += wsy * ry; acc[12] += wsy * rz;
      acc[13] += wsz * rx; acc[14] += wsz * ry; acc[15] += wsz * rz;
    }
#pragma unroll
    for (int k = 0; k < 16; ++k)
      for (int o = 32; o; o >>= 1) acc[k] += __shfl_down(acc[k], o, 64);
    if (lane == 0) {
#pragma unroll
      for (int k = 0; k < 16; ++k) red[w][k] = acc[k];
    }
    __syncthreads();
    double s16[16];
#pragma unroll
    for (int k = 0; k < 16; ++k)
      s16[k] = red[0][k] + red[1][k] + red[2][k] + red[3][k] +
               red[4][k] + red[5][k] + red[6][k] + red[7][k];
    kabsch_from_sums(s16[0], s16 + 1, s16 + 4, s16 + 7, T);  // all threads, lockstep
    __syncthreads();   // red[] reused next iteration
  }
  if (tid == 0) {
    out[10500 + 0]  = (float)T[0]; out[10500 + 1]  = (float)T[1];
    out[10500 + 2]  = (float)T[2]; out[10500 + 3]  = (float)T[9];
    out[10500 + 4]  = (float)T[3]; out[10500 + 5]  = (float)T[4];
    out[10500 + 6]  = (float)T[5]; out[10500 + 7]  = (float)T[10];
    out[10500 + 8]  = (float)T[6]; out[10500 + 9]  = (float)T[7];
    out[10500 + 10] = (float)T[8]; out[10500 + 11] = (float)T[11];
    out[10500 + 12] = 0.f; out[10500 + 13] = 0.f;
    out[10500 + 14] = 0.f; out[10500 + 15] = 1.f;
  }
}

extern "C" void kernel_launch(void* const* d_in, const int* in_sizes, int n_in,
                              void* d_out, int out_size, void* d_ws, size_t ws_size,
                              hipStream_t stream) {
  const float* refp = (const float*)d_in[0];
  const float* srcp = (const float*)d_in[1];
  const void* mref = d_in[2];
  const void* msrc = d_in[3];
  const float* scores = (const float*)d_in[4];
  float* out = (float*)d_out;
  char* ws = (char*)d_ws;
  unsigned* ccnt = (unsigned*)(ws + OFF_CCNT);
  int* icount = (int*)(ws + OFF_ICNT);
  double* trans = (double*)(ws + OFF_TRANS);
  float* pool = (float*)(ws + OFF_POOL);
  unsigned* hdr = (unsigned*)(ws + OFF_HDR);
  unsigned long long* sel = (unsigned long long*)(ws + OFF_SEL);
  unsigned* phist = (unsigned*)(ws + OFF_PHIST);
  unsigned long long* clist = (unsigned long long*)(ws + OFF_CLIST);

  k_fused<<<PP, 256, 0, stream>>>(scores, mref, msrc, ccnt, clist);
  k_hist<<<64, 256, 0, stream>>>(ccnt, clist, phist);
  k_cut<<<1, 1024, 0, stream>>>(phist, hdr);
  k_gather<<<64, 256, 0, stream>>>(ccnt, clist, hdr, sel);
  k_sortout<<<1, 1024, 0, stream>>>(sel, hdr, refp, srcp, pool, out);
  k_evalT<<<PP, 256, 0, stream>>>(ccnt, clist, refp, srcp, pool, trans, icount);
  k_refine<<<1, 512, 0, stream>>>(trans, icount, pool, out);
}